// Round 1
// baseline (223.246 us; speedup 1.0000x reference)
//
#include <hip/hip_runtime.h>

#define NNODES 200000
#define NQ     128
#define EPQ    1024
#define NE     (NQ*EPQ)
#define TOPK   128
#define NSEL   (NQ*TOPK)

// ---------------- helpers ----------------
__device__ __forceinline__ unsigned fkey(float f) {
  unsigned u = __float_as_uint(f);
  return (u & 0x80000000u) ? ~u : (u | 0x80000000u);
}
__device__ __forceinline__ float fdecode(unsigned k) {
  unsigned u = (k & 0x80000000u) ? (k ^ 0x80000000u) : ~k;
  return __uint_as_float(u);
}
__device__ __forceinline__ void fmarow(float* a, float x, const float4 n0, const float4 n1) {
  a[0] = fmaf(x, n0.x, a[0]); a[1] = fmaf(x, n0.y, a[1]);
  a[2] = fmaf(x, n0.z, a[2]); a[3] = fmaf(x, n0.w, a[3]);
  a[4] = fmaf(x, n1.x, a[4]); a[5] = fmaf(x, n1.y, a[5]);
  a[6] = fmaf(x, n1.z, a[6]); a[7] = fmaf(x, n1.w, a[7]);
}

// ---------------- N = WqL^T * WkL  (128x128) ----------------
__global__ __launch_bounds__(256) void k_nmat(const float* __restrict__ Wq,
                                              const float* __restrict__ Wk,
                                              float* __restrict__ Nm) {
  const int id = blockIdx.x * 256 + threadIdx.x;   // 0..16383
  const int j = id >> 7, k = id & 127;
  float a = 0.f;
  for (int i = 0; i < 256; ++i)
    a = fmaf(Wq[i * 256 + j], Wk[i * 256 + k], a);
  Nm[j * 128 + k] = a;
}

// ---------------- per-query alpha/beta/c ----------------
__global__ __launch_bounds__(256) void k_query(const float* __restrict__ Wq,
                                               const float* __restrict__ Wk,
                                               const float* __restrict__ qs_emb,
                                               const float* __restrict__ qr_emb,
                                               float* __restrict__ alpha,
                                               float* __restrict__ beta,
                                               float* __restrict__ cv) {
  __shared__ float sq[128];
  __shared__ float u[256], v[256];
  const int q = blockIdx.x, t = threadIdx.x;
  if (t < 64) sq[t] = qs_emb[q * 64 + t];
  else if (t < 128) sq[t] = qr_emb[q * 64 + (t - 64)];
  __syncthreads();
  {
    const float* wq = Wq + t * 256 + 128;
    const float* wk = Wk + t * 256 + 128;
    float uu = 0.f, vv = 0.f;
    for (int j = 0; j < 128; ++j) {
      uu = fmaf(wq[j], sq[j], uu);
      vv = fmaf(wk[j], sq[j], vv);
    }
    u[t] = uu; v[t] = vv;
  }
  __syncthreads();
  if (t < 128) {
    float a = 0.f;
    for (int i = 0; i < 256; ++i) a = fmaf(Wq[i * 256 + t], v[i], a);
    alpha[q * 128 + t] = a;
  } else {
    const int k = t - 128;
    float b = 0.f;
    for (int i = 0; i < 256; ++i) b = fmaf(u[i], Wk[i * 256 + k], b);
    beta[q * 128 + k] = b;
  }
  __syncthreads();
  if (t < 64) {
    float c = u[t] * v[t] + u[t + 64] * v[t + 64] + u[t + 128] * v[t + 128] + u[t + 192] * v[t + 192];
    c += __shfl_xor(c, 32, 64);
    c += __shfl_xor(c, 16, 64);
    c += __shfl_xor(c, 8, 64);
    c += __shfl_xor(c, 4, 64);
    c += __shfl_xor(c, 2, 64);
    c += __shfl_xor(c, 1, 64);
    if (t == 0) cv[q] = c;
  }
}

// ---------------- edge logits: logit = x^T N y + a.x + b.y + c ----------------
// 64 edges/block, 256 threads, thread tile = 4 edges x 8 k.
__global__ __launch_bounds__(256, 4) void k_logits(
    const float* __restrict__ repr, const float* __restrict__ rel,
    const int* __restrict__ edges, const float* __restrict__ Nm,
    const float* __restrict__ alpha, const float* __restrict__ beta,
    const float* __restrict__ cv, float* __restrict__ logits) {
  __shared__ float St[64][64];   // src rows transposed: St[j][e]
  __shared__ float Rt[64][64];   // rel rows transposed
  __shared__ float sA[128], sB[128];
  __shared__ int sSrc[64], sDst[64];
  const int t = threadIdx.x;
  const int e0 = blockIdx.x * 64;
  const int q = e0 >> 10;

  {
    const int el = t & 63;
    const int jq = t >> 6;                 // 0..3 (16 j's each)
    const int e = e0 + el;
    const int src = edges[e * 8 + 6];
    const int dst = edges[e * 8 + 7];
    if (jq == 0) { sSrc[el] = src; sDst[el] = dst; }
    const float4* ps = (const float4*)(repr + (size_t)src * 64 + jq * 16);
    const float4* pr = (const float4*)(rel + (size_t)e * 64 + jq * 16);
#pragma unroll
    for (int i = 0; i < 4; ++i) {
      float4 s = ps[i];
      float4 r = pr[i];
      const int j = jq * 16 + i * 4;
      St[j + 0][el] = s.x; St[j + 1][el] = s.y; St[j + 2][el] = s.z; St[j + 3][el] = s.w;
      Rt[j + 0][el] = r.x; Rt[j + 1][el] = r.y; Rt[j + 2][el] = r.z; Rt[j + 3][el] = r.w;
    }
    if (t < 128) sA[t] = alpha[q * 128 + t];
    else         sB[t - 128] = beta[q * 128 + (t - 128)];
  }
  __syncthreads();

  const int kg = t & 15, eg = t >> 4;
  const int k0 = kg * 8, eb = eg * 4;
  float acc[4][8];
#pragma unroll
  for (int i = 0; i < 4; ++i)
#pragma unroll
    for (int m = 0; m < 8; ++m) acc[i][m] = 0.f;

  const float* __restrict__ Np = Nm + k0;
#pragma unroll 4
  for (int j = 0; j < 64; ++j) {
    const float4 n0 = *(const float4*)(Np + j * 128);
    const float4 n1 = *(const float4*)(Np + j * 128 + 4);
    const float4 xv = *(const float4*)(&St[j][eb]);
    fmarow(acc[0], xv.x, n0, n1);
    fmarow(acc[1], xv.y, n0, n1);
    fmarow(acc[2], xv.z, n0, n1);
    fmarow(acc[3], xv.w, n0, n1);
  }
#pragma unroll 4
  for (int j = 0; j < 64; ++j) {
    const float4 n0 = *(const float4*)(Np + (64 + j) * 128);
    const float4 n1 = *(const float4*)(Np + (64 + j) * 128 + 4);
    const float4 xv = *(const float4*)(&Rt[j][eb]);
    fmarow(acc[0], xv.x, n0, n1);
    fmarow(acc[1], xv.y, n0, n1);
    fmarow(acc[2], xv.z, n0, n1);
    fmarow(acc[3], xv.w, n0, n1);
  }

  float aA[8], aB[8];
#pragma unroll
  for (int m = 0; m < 8; ++m) { aA[m] = sA[k0 + m]; aB[m] = sB[k0 + m]; }

  float part[4];
#pragma unroll
  for (int i = 0; i < 4; ++i) {
    const int el = eb + i;
    const int e = e0 + el;
    const float* xp;
    const float* yp;
    if (k0 < 64) {
      xp = repr + (size_t)sSrc[el] * 64 + k0;
      yp = repr + (size_t)sDst[el] * 64 + k0;
    } else {
      xp = rel + (size_t)e * 64 + (k0 - 64);
      yp = xp;
    }
    const float4 x0 = *(const float4*)xp;
    const float4 x1 = *(const float4*)(xp + 4);
    const float4 y0 = *(const float4*)yp;
    const float4 y1 = *(const float4*)(yp + 4);
    const float xs[8] = {x0.x, x0.y, x0.z, x0.w, x1.x, x1.y, x1.z, x1.w};
    const float ys[8] = {y0.x, y0.y, y0.z, y0.w, y1.x, y1.y, y1.z, y1.w};
    float p = 0.f;
#pragma unroll
    for (int m = 0; m < 8; ++m)
      p += (acc[i][m] + aB[m]) * ys[m] + aA[m] * xs[m];
    part[i] = p;
  }
#pragma unroll
  for (int i = 0; i < 4; ++i) {
    float p = part[i];
    p += __shfl_xor(p, 8, 64);
    p += __shfl_xor(p, 4, 64);
    p += __shfl_xor(p, 2, 64);
    p += __shfl_xor(p, 1, 64);
    part[i] = p;
  }
  if (kg == 0) {
    const float c = cv[q];
#pragma unroll
    for (int i = 0; i < 4; ++i) logits[e0 + eb + i] = part[i] + c;
  }
}

// ---------------- segment softmax (by src) ----------------
__global__ __launch_bounds__(256) void k_segmax(const float* __restrict__ logits,
                                                const int* __restrict__ edges,
                                                unsigned* __restrict__ segmax) {
  const int e = blockIdx.x * 256 + threadIdx.x;
  const int src = edges[e * 8 + 6];
  atomicMax(&segmax[src], fkey(logits[e]));
}

__global__ __launch_bounds__(256) void k_exsum(float* __restrict__ logits,
                                               const int* __restrict__ edges,
                                               const unsigned* __restrict__ segmax,
                                               float* __restrict__ segsum) {
  const int e = blockIdx.x * 256 + threadIdx.x;
  const int src = edges[e * 8 + 6];
  const float m = fdecode(segmax[src]);
  const float ex = expf(logits[e] - m);
  logits[e] = ex;                       // in-place: now holds exp(l - m)
  atomicAdd(&segsum[src], ex);
}

// ---------------- per-query top-128 (bitonic, exact tie-break) ----------------
__global__ __launch_bounds__(256) void k_topk(const float* __restrict__ ex,
                                              const float* __restrict__ segsum,
                                              const int* __restrict__ edges,
                                              const float* __restrict__ node_score,
                                              int* __restrict__ sel,
                                              int* __restrict__ flag,
                                              float* __restrict__ out_score,
                                              float* agg) {
  __shared__ unsigned long long key[1024];
  __shared__ int selEl[128];
  const int q = blockIdx.x, t = threadIdx.x;
  for (int i = t; i < 1024; i += 256) {
    const int e = q * 1024 + i;
    const int src = edges[e * 8 + 6];
    const float ts = (ex[e] / segsum[src]) * node_score[src];
    key[i] = ((unsigned long long)__float_as_uint(ts) << 32) | (unsigned)(1023 - i);
  }
  __syncthreads();
  for (int k = 2; k <= 1024; k <<= 1) {
    for (int j = k >> 1; j > 0; j >>= 1) {
      for (int i = t; i < 1024; i += 256) {
        const int ixj = i ^ j;
        if (ixj > i) {
          const unsigned long long a = key[i], b = key[ixj];
          const bool up = (i & k) == 0;            // descending sort
          if (up ? (a < b) : (a > b)) { key[i] = b; key[ixj] = a; }
        }
      }
      __syncthreads();
    }
  }
  if (t < 128) {
    const int el = 1023 - (int)(unsigned)(key[t] & 0xFFFFFFFFull);
    selEl[t] = el;
    const int e = q * 1024 + el;
    sel[q * 128 + t] = e;
    const int src = edges[e * 8 + 6];
    const int dst = edges[e * 8 + 7];
    const float soft = ex[e] / segsum[src];
    atomicAdd(&out_score[dst], soft * node_score[src]);
    flag[src] = 1;
  }
  __syncthreads();
  // zero agg rows for selected src (all zeroing precedes all adds: next kernel)
  for (int i = t; i < 128 * 64; i += 256) {
    const int s = i >> 6, d = i & 63;
    const int e = q * 1024 + selEl[s];
    const int src = edges[e * 8 + 6];
    agg[(size_t)src * 64 + d] = 0.f;
  }
}

// ---------------- scatter: agg[src] += soft * repr[dst] ----------------
__global__ __launch_bounds__(256) void k_scatter(const int* __restrict__ sel,
                                                 const int* __restrict__ edges,
                                                 const float* __restrict__ ex,
                                                 const float* __restrict__ segsum,
                                                 const float* __restrict__ repr,
                                                 float* agg) {
  const int i = blockIdx.x * 4 + (threadIdx.x >> 6);   // selected slot
  const int d = threadIdx.x & 63;
  const int e = sel[i];
  const int src = edges[e * 8 + 6];
  const int dst = edges[e * 8 + 7];
  const float soft = ex[e] / segsum[src];
  atomicAdd(&agg[(size_t)src * 64 + d], soft * repr[(size_t)dst * 64 + d]);
}

// ---------------- final: out = leakyrelu(upd @ W_lin + b) ----------------
#define FN 192
__global__ __launch_bounds__(192) void k_final(const float* __restrict__ repr,
                                               const float* agg,      // aliases outr
                                               const int* __restrict__ flag,
                                               const float* __restrict__ Wl,
                                               const float* __restrict__ bl,
                                               float* outr) {
  __shared__ float Ut[64][FN];
  __shared__ float W[64][64];
  __shared__ float bs[64];
  const int t = threadIdx.x;
  const int n0blk = blockIdx.x * FN;
  for (int i = t; i < 4096; i += FN) W[i >> 6][i & 63] = Wl[i];
  if (t < 64) bs[t] = bl[t];
  {
    const int n = n0blk + t;
    const bool ok = n < NNODES;
    const float* rowp = repr;
    if (ok) rowp = (flag[n] ? agg : repr) + (size_t)n * 64;
#pragma unroll
    for (int i = 0; i < 16; ++i) {
      float4 v4 = ok ? ((const float4*)rowp)[i] : float4{0.f, 0.f, 0.f, 0.f};
      const int c = i * 4;
      Ut[c + 0][t] = v4.x; Ut[c + 1][t] = v4.y; Ut[c + 2][t] = v4.z; Ut[c + 3][t] = v4.w;
    }
  }
  __syncthreads();
  const int dg = t & 7, ng = t >> 3;       // 8 d-groups x 24 n-groups
  const int d0 = dg * 8, nb = ng * 8;
  float acc[8][8];
#pragma unroll
  for (int i = 0; i < 8; ++i)
#pragma unroll
    for (int m = 0; m < 8; ++m) acc[i][m] = 0.f;
#pragma unroll 2
  for (int c = 0; c < 64; ++c) {
    const float4 w0 = *(const float4*)&W[c][d0];
    const float4 w1 = *(const float4*)&W[c][d0 + 4];
    const float4 u0 = *(const float4*)&Ut[c][nb];
    const float4 u1 = *(const float4*)&Ut[c][nb + 4];
    fmarow(acc[0], u0.x, w0, w1);
    fmarow(acc[1], u0.y, w0, w1);
    fmarow(acc[2], u0.z, w0, w1);
    fmarow(acc[3], u0.w, w0, w1);
    fmarow(acc[4], u1.x, w0, w1);
    fmarow(acc[5], u1.y, w0, w1);
    fmarow(acc[6], u1.z, w0, w1);
    fmarow(acc[7], u1.w, w0, w1);
  }
  float bb[8];
#pragma unroll
  for (int m = 0; m < 8; ++m) bb[m] = bs[d0 + m];
#pragma unroll
  for (int i = 0; i < 8; ++i) {
    const int n = n0blk + nb + i;
    if (n < NNODES) {
      float o[8];
#pragma unroll
      for (int m = 0; m < 8; ++m) {
        float v = acc[i][m] + bb[m];
        o[m] = v > 0.f ? v : 0.01f * v;
      }
      float4 o0 = {o[0], o[1], o[2], o[3]};
      float4 o1 = {o[4], o[5], o[6], o[7]};
      *(float4*)(outr + (size_t)n * 64 + d0) = o0;
      *(float4*)(outr + (size_t)n * 64 + d0 + 4) = o1;
    }
  }
}

// ---------------- launcher ----------------
extern "C" void kernel_launch(void* const* d_in, const int* in_sizes, int n_in,
                              void* d_out, int out_size, void* d_ws, size_t ws_size,
                              hipStream_t stream) {
  const float* node_score = (const float*)d_in[0];
  const float* node_repr  = (const float*)d_in[1];
  const float* rel_emb    = (const float*)d_in[2];
  const float* qs_emb     = (const float*)d_in[3];
  const float* qr_emb     = (const float*)d_in[4];
  const float* Wq         = (const float*)d_in[5];
  const float* Wk         = (const float*)d_in[6];
  const float* Wl         = (const float*)d_in[7];
  const float* bl         = (const float*)d_in[8];
  const int*   edges      = (const int*)d_in[9];

  float* out_score = (float*)d_out;                 // [200000]
  float* out_repr  = out_score + NNODES;            // [200000 x 64]; doubles as agg

  float* ws = (float*)d_ws;
  size_t o = 0;
  float* Nm      = ws + o; o += 128 * 128;
  float* alpha   = ws + o; o += NQ * 128;
  float* beta    = ws + o; o += NQ * 128;
  float* cv      = ws + o; o += NQ;
  float* exl     = ws + o; o += NE;                 // logits, then exp(l-m)
  unsigned* segmax = (unsigned*)(ws + o); o += NNODES;
  float* segsum  = ws + o; o += NNODES;
  int* sel       = (int*)(ws + o); o += NSEL;
  int* flag      = (int*)(ws + o); o += NNODES;

  hipMemsetAsync(segmax, 0, NNODES * sizeof(unsigned), stream);   // key(x) > 0 for all finite x
  hipMemsetAsync(segsum, 0, NNODES * sizeof(float), stream);
  hipMemsetAsync(flag, 0, NNODES * sizeof(int), stream);
  hipMemsetAsync(out_score, 0, NNODES * sizeof(float), stream);

  k_nmat<<<64, 256, 0, stream>>>(Wq, Wk, Nm);
  k_query<<<NQ, 256, 0, stream>>>(Wq, Wk, qs_emb, qr_emb, alpha, beta, cv);
  k_logits<<<NE / 64, 256, 0, stream>>>(node_repr, rel_emb, edges, Nm, alpha, beta, cv, exl);
  k_segmax<<<NE / 256, 256, 0, stream>>>(exl, edges, segmax);
  k_exsum<<<NE / 256, 256, 0, stream>>>(exl, edges, segmax, segsum);
  k_topk<<<NQ, 256, 0, stream>>>(exl, segsum, edges, node_score, sel, flag, out_score, out_repr);
  k_scatter<<<NSEL / 4, 256, 0, stream>>>(sel, edges, exl, segsum, node_repr, out_repr);
  k_final<<<(NNODES + FN - 1) / FN, FN, 0, stream>>>(node_repr, out_repr, flag, Wl, bl, out_repr);
}

// Round 2
// 208.988 us; speedup vs baseline: 1.0682x; 1.0682x over previous
//
#include <hip/hip_runtime.h>

#define NNODES 200000
#define NQ     128
#define EPQ    1024
#define NE     (NQ*EPQ)
#define TOPK   128
#define NSEL   (NQ*TOPK)

// ---------------- helpers ----------------
__device__ __forceinline__ unsigned fkey(float f) {
  unsigned u = __float_as_uint(f);
  return (u & 0x80000000u) ? ~u : (u | 0x80000000u);
}
__device__ __forceinline__ float fdecode(unsigned k) {
  unsigned u = (k & 0x80000000u) ? (k ^ 0x80000000u) : ~k;
  return __uint_as_float(u);
}
__device__ __forceinline__ void fmarow(float* a, float x, const float4 n0, const float4 n1) {
  a[0] = fmaf(x, n0.x, a[0]); a[1] = fmaf(x, n0.y, a[1]);
  a[2] = fmaf(x, n0.z, a[2]); a[3] = fmaf(x, n0.w, a[3]);
  a[4] = fmaf(x, n1.x, a[4]); a[5] = fmaf(x, n1.y, a[5]);
  a[6] = fmaf(x, n1.z, a[6]); a[7] = fmaf(x, n1.w, a[7]);
}

typedef const __attribute__((address_space(1))) void* gas_ptr;
typedef __attribute__((address_space(3))) void* las_ptr;
__device__ __forceinline__ void gload16(const void* g, void* l) {
  __builtin_amdgcn_global_load_lds((gas_ptr)g, (las_ptr)l, 16, 0, 0);
}

// permuted within-row index for Nm: lane kg reads k=8kg..8kg+7 via two
// conflict-free ds_read_b128 at byte kg*16 and 256+kg*16 of the 512B row.
__device__ __forceinline__ int nperm(int k) {
  const int q = k >> 2, p = k & 3;
  return (q & 1) * 64 + (q >> 1) * 4 + p;
}

// ---------------- N = WqL^T * WkL  (128x128, permuted row layout) ----------------
__global__ __launch_bounds__(256) void k_nmat(const float* __restrict__ Wq,
                                              const float* __restrict__ Wk,
                                              float* __restrict__ Nm) {
  const int id = blockIdx.x * 256 + threadIdx.x;   // 0..16383
  const int j = id >> 7, k = id & 127;
  float a0 = 0.f, a1 = 0.f, a2 = 0.f, a3 = 0.f;
  for (int i = 0; i < 256; i += 4) {
    a0 = fmaf(Wq[(i + 0) * 256 + j], Wk[(i + 0) * 256 + k], a0);
    a1 = fmaf(Wq[(i + 1) * 256 + j], Wk[(i + 1) * 256 + k], a1);
    a2 = fmaf(Wq[(i + 2) * 256 + j], Wk[(i + 2) * 256 + k], a2);
    a3 = fmaf(Wq[(i + 3) * 256 + j], Wk[(i + 3) * 256 + k], a3);
  }
  Nm[j * 128 + nperm(k)] = (a0 + a1) + (a2 + a3);
}

// ---------------- per-query alpha/beta/c ----------------
__global__ __launch_bounds__(256) void k_query(const float* __restrict__ Wq,
                                               const float* __restrict__ Wk,
                                               const float* __restrict__ qs_emb,
                                               const float* __restrict__ qr_emb,
                                               float* __restrict__ alpha,
                                               float* __restrict__ beta,
                                               float* __restrict__ cv) {
  __shared__ float sq[128];
  __shared__ float u[256], v[256];
  const int q = blockIdx.x, t = threadIdx.x;
  if (t < 64) sq[t] = qs_emb[q * 64 + t];
  else if (t < 128) sq[t] = qr_emb[q * 64 + (t - 64)];
  __syncthreads();
  {
    const float* wq = Wq + t * 256 + 128;
    const float* wk = Wk + t * 256 + 128;
    float uu = 0.f, vv = 0.f;
    for (int j = 0; j < 128; ++j) {
      uu = fmaf(wq[j], sq[j], uu);
      vv = fmaf(wk[j], sq[j], vv);
    }
    u[t] = uu; v[t] = vv;
  }
  __syncthreads();
  if (t < 128) {
    float a = 0.f;
    for (int i = 0; i < 256; ++i) a = fmaf(Wq[i * 256 + t], v[i], a);
    alpha[q * 128 + t] = a;
  } else {
    const int k = t - 128;
    float b = 0.f;
    for (int i = 0; i < 256; ++i) b = fmaf(u[i], Wk[i * 256 + k], b);
    beta[q * 128 + k] = b;
  }
  __syncthreads();
  if (t < 64) {
    float c = u[t] * v[t] + u[t + 64] * v[t + 64] + u[t + 128] * v[t + 128] + u[t + 192] * v[t + 192];
    c += __shfl_xor(c, 32, 64);
    c += __shfl_xor(c, 16, 64);
    c += __shfl_xor(c, 8, 64);
    c += __shfl_xor(c, 4, 64);
    c += __shfl_xor(c, 2, 64);
    c += __shfl_xor(c, 1, 64);
    if (t == 0) cv[q] = c;
  }
}

// ---------------- edge logits: logit = x^T N y + a.x + b.y + c ----------------
// 64 edges/block, 256 threads, thread tile = 4 edges x 8 k.
// N streamed through LDS in 8 double-buffered chunks of 16 rows (8KB).
__global__ __launch_bounds__(256, 4) void k_logits(
    const float* __restrict__ repr, const float* __restrict__ rel,
    const int* __restrict__ edges, const float* __restrict__ Nm,
    const float* __restrict__ alpha, const float* __restrict__ beta,
    const float* __restrict__ cv, float* __restrict__ logits) {
  __shared__ float St[64][64];       // src rows transposed: St[j][e]
  __shared__ float Rt[64][64];       // rel rows transposed
  __shared__ float Nb[2][2048];      // double-buffered N chunk (16 rows x 128 f, permuted)
  __shared__ float sA[128], sB[128];
  __shared__ int sSrc[64], sDst[64];
  const int t = threadIdx.x;
  const int e0 = blockIdx.x * 64;
  const int q = e0 >> 10;

  // issue chunk 0 N loads first (overlap with X staging below)
  {
    const char* g = (const char*)Nm + (size_t)t * 16;
    char* l = (char*)&Nb[0][0] + (t >> 6) * 1024;
    gload16(g, l);
    gload16(g + 4096, l + 4096);
  }

  {
    const int el = t & 63;
    const int jq = t >> 6;                 // 0..3 (16 j's each)
    const int e = e0 + el;
    const int src = edges[e * 8 + 6];
    const int dst = edges[e * 8 + 7];
    if (jq == 0) { sSrc[el] = src; sDst[el] = dst; }
    const float4* ps = (const float4*)(repr + (size_t)src * 64 + jq * 16);
    const float4* pr = (const float4*)(rel + (size_t)e * 64 + jq * 16);
#pragma unroll
    for (int i = 0; i < 4; ++i) {
      float4 s = ps[i];
      float4 r = pr[i];
      const int j = jq * 16 + i * 4;
      St[j + 0][el] = s.x; St[j + 1][el] = s.y; St[j + 2][el] = s.z; St[j + 3][el] = s.w;
      Rt[j + 0][el] = r.x; Rt[j + 1][el] = r.y; Rt[j + 2][el] = r.z; Rt[j + 3][el] = r.w;
    }
    if (t < 128) sA[t] = alpha[q * 128 + t];
    else         sB[t - 128] = beta[q * 128 + (t - 128)];
  }
  __syncthreads();   // drains vmcnt: chunk 0 resident, X tiles resident

  const int kg = t & 15, eg = t >> 4;
  const int k0 = kg * 8, eb = eg * 4;
  const int kf = kg * 4;                   // float offset within permuted 128-f row
  float acc[4][8];
#pragma unroll
  for (int i = 0; i < 4; ++i)
#pragma unroll
    for (int m = 0; m < 8; ++m) acc[i][m] = 0.f;

  for (int ch = 0; ch < 8; ++ch) {
    if (ch < 7) {
      const char* g = (const char*)Nm + (ch + 1) * 8192 + (size_t)t * 16;
      char* l = (char*)&Nb[(ch + 1) & 1][0] + (t >> 6) * 1024;
      gload16(g, l);
      gload16(g + 4096, l + 4096);
    }
    const float* __restrict__ Xb = (ch < 4) ? &St[0][0] : &Rt[0][0];
    const float* __restrict__ Xrow = Xb + (ch & 3) * 16 * 64;
    const float* __restrict__ Nrow = &Nb[ch & 1][0];
#pragma unroll 4
    for (int jl = 0; jl < 16; ++jl) {
      const float4 n0 = *(const float4*)(Nrow + jl * 128 + kf);
      const float4 n1 = *(const float4*)(Nrow + jl * 128 + 64 + kf);
      const float4 xv = *(const float4*)(Xrow + jl * 64 + eb);
      fmarow(acc[0], xv.x, n0, n1);
      fmarow(acc[1], xv.y, n0, n1);
      fmarow(acc[2], xv.z, n0, n1);
      fmarow(acc[3], xv.w, n0, n1);
    }
    __syncthreads();   // drains vmcnt(0): next chunk resident; orders buffer reuse
  }

  float aA[8], aB[8];
#pragma unroll
  for (int m = 0; m < 8; ++m) { aA[m] = sA[k0 + m]; aB[m] = sB[k0 + m]; }

  float part[4];
#pragma unroll
  for (int i = 0; i < 4; ++i) {
    const int el = eb + i;
    const int e = e0 + el;
    const float* xp;
    const float* yp;
    if (k0 < 64) {
      xp = repr + (size_t)sSrc[el] * 64 + k0;
      yp = repr + (size_t)sDst[el] * 64 + k0;
    } else {
      xp = rel + (size_t)e * 64 + (k0 - 64);
      yp = xp;
    }
    const float4 x0 = *(const float4*)xp;
    const float4 x1 = *(const float4*)(xp + 4);
    const float4 y0 = *(const float4*)yp;
    const float4 y1 = *(const float4*)(yp + 4);
    const float xs[8] = {x0.x, x0.y, x0.z, x0.w, x1.x, x1.y, x1.z, x1.w};
    const float ys[8] = {y0.x, y0.y, y0.z, y0.w, y1.x, y1.y, y1.z, y1.w};
    float p = 0.f;
#pragma unroll
    for (int m = 0; m < 8; ++m)
      p += (acc[i][m] + aB[m]) * ys[m] + aA[m] * xs[m];
    part[i] = p;
  }
#pragma unroll
  for (int i = 0; i < 4; ++i) {
    float p = part[i];
    p += __shfl_xor(p, 8, 64);
    p += __shfl_xor(p, 4, 64);
    p += __shfl_xor(p, 2, 64);
    p += __shfl_xor(p, 1, 64);
    part[i] = p;
  }
  if (kg == 0) {
    const float cq = cv[q];
#pragma unroll
    for (int i = 0; i < 4; ++i) logits[e0 + eb + i] = part[i] + cq;
  }
}

// ---------------- segment softmax (by src) ----------------
__global__ __launch_bounds__(256) void k_segmax(const float* __restrict__ logits,
                                                const int* __restrict__ edges,
                                                unsigned* __restrict__ segmax) {
  const int e = blockIdx.x * 256 + threadIdx.x;
  const int src = edges[e * 8 + 6];
  atomicMax(&segmax[src], fkey(logits[e]));
}

__global__ __launch_bounds__(256) void k_exsum(float* __restrict__ logits,
                                               const int* __restrict__ edges,
                                               const unsigned* __restrict__ segmax,
                                               float* __restrict__ segsum) {
  const int e = blockIdx.x * 256 + threadIdx.x;
  const int src = edges[e * 8 + 6];
  const float m = fdecode(segmax[src]);
  const float ex = expf(logits[e] - m);
  logits[e] = ex;                       // in-place: now holds exp(l - m)
  atomicAdd(&segsum[src], ex);
}

// ---------------- per-query top-128 (bitonic, exact tie-break) ----------------
__global__ __launch_bounds__(256) void k_topk(const float* __restrict__ ex,
                                              const float* __restrict__ segsum,
                                              const int* __restrict__ edges,
                                              const float* __restrict__ node_score,
                                              int* __restrict__ sel,
                                              int* __restrict__ flag,
                                              float* __restrict__ out_score,
                                              float* agg) {
  __shared__ unsigned long long key[1024];
  __shared__ int selEl[128];
  const int q = blockIdx.x, t = threadIdx.x;
  for (int i = t; i < 1024; i += 256) {
    const int e = q * 1024 + i;
    const int src = edges[e * 8 + 6];
    const float ts = (ex[e] / segsum[src]) * node_score[src];
    key[i] = ((unsigned long long)__float_as_uint(ts) << 32) | (unsigned)(1023 - i);
  }
  __syncthreads();
  for (int k = 2; k <= 1024; k <<= 1) {
    for (int j = k >> 1; j > 0; j >>= 1) {
      for (int i = t; i < 1024; i += 256) {
        const int ixj = i ^ j;
        if (ixj > i) {
          const unsigned long long a = key[i], b = key[ixj];
          const bool up = (i & k) == 0;            // descending sort
          if (up ? (a < b) : (a > b)) { key[i] = b; key[ixj] = a; }
        }
      }
      __syncthreads();
    }
  }
  if (t < 128) {
    const int el = 1023 - (int)(unsigned)(key[t] & 0xFFFFFFFFull);
    selEl[t] = el;
    const int e = q * 1024 + el;
    sel[q * 128 + t] = e;
    const int src = edges[e * 8 + 6];
    const int dst = edges[e * 8 + 7];
    const float soft = ex[e] / segsum[src];
    atomicAdd(&out_score[dst], soft * node_score[src]);
    flag[src] = 1;
  }
  __syncthreads();
  // zero agg rows for selected src (all zeroing precedes all adds: next kernel)
  for (int i = t; i < 128 * 64; i += 256) {
    const int s = i >> 6, d = i & 63;
    const int e = q * 1024 + selEl[s];
    const int src = edges[e * 8 + 6];
    agg[(size_t)src * 64 + d] = 0.f;
  }
}

// ---------------- scatter: agg[src] += soft * repr[dst] ----------------
__global__ __launch_bounds__(256) void k_scatter(const int* __restrict__ sel,
                                                 const int* __restrict__ edges,
                                                 const float* __restrict__ ex,
                                                 const float* __restrict__ segsum,
                                                 const float* __restrict__ repr,
                                                 float* agg) {
  const int i = blockIdx.x * 4 + (threadIdx.x >> 6);   // selected slot
  const int d = threadIdx.x & 63;
  const int e = sel[i];
  const int src = edges[e * 8 + 6];
  const int dst = edges[e * 8 + 7];
  const float soft = ex[e] / segsum[src];
  atomicAdd(&agg[(size_t)src * 64 + d], soft * repr[(size_t)dst * 64 + d]);
}

// ---------------- final: out = leakyrelu(upd @ W_lin + b) ----------------
#define FN 192
__global__ __launch_bounds__(192) void k_final(const float* __restrict__ repr,
                                               const float* agg,      // aliases outr
                                               const int* __restrict__ flag,
                                               const float* __restrict__ Wl,
                                               const float* __restrict__ bl,
                                               float* outr) {
  __shared__ float Ut[64][FN];
  __shared__ float W[64][64];
  __shared__ float bs[64];
  const int t = threadIdx.x;
  const int n0blk = blockIdx.x * FN;
  for (int i = t; i < 4096; i += FN) W[i >> 6][i & 63] = Wl[i];
  if (t < 64) bs[t] = bl[t];
  {
    const int n = n0blk + t;
    const bool ok = n < NNODES;
    const float* rowp = repr;
    if (ok) rowp = (flag[n] ? agg : repr) + (size_t)n * 64;
#pragma unroll
    for (int i = 0; i < 16; ++i) {
      float4 v4 = ok ? ((const float4*)rowp)[i] : float4{0.f, 0.f, 0.f, 0.f};
      const int c = i * 4;
      Ut[c + 0][t] = v4.x; Ut[c + 1][t] = v4.y; Ut[c + 2][t] = v4.z; Ut[c + 3][t] = v4.w;
    }
  }
  __syncthreads();
  const int dg = t & 7, ng = t >> 3;       // 8 d-groups x 24 n-groups
  const int d0 = dg * 8, nb = ng * 8;
  float acc[8][8];
#pragma unroll
  for (int i = 0; i < 8; ++i)
#pragma unroll
    for (int m = 0; m < 8; ++m) acc[i][m] = 0.f;
#pragma unroll 2
  for (int c = 0; c < 64; ++c) {
    const float4 w0 = *(const float4*)&W[c][d0];
    const float4 w1 = *(const float4*)&W[c][d0 + 4];
    const float4 u0 = *(const float4*)&Ut[c][nb];
    const float4 u1 = *(const float4*)&Ut[c][nb + 4];
    fmarow(acc[0], u0.x, w0, w1);
    fmarow(acc[1], u0.y, w0, w1);
    fmarow(acc[2], u0.z, w0, w1);
    fmarow(acc[3], u0.w, w0, w1);
    fmarow(acc[4], u1.x, w0, w1);
    fmarow(acc[5], u1.y, w0, w1);
    fmarow(acc[6], u1.z, w0, w1);
    fmarow(acc[7], u1.w, w0, w1);
  }
  float bb[8];
#pragma unroll
  for (int m = 0; m < 8; ++m) bb[m] = bs[d0 + m];
#pragma unroll
  for (int i = 0; i < 8; ++i) {
    const int n = n0blk + nb + i;
    if (n < NNODES) {
      float o[8];
#pragma unroll
      for (int m = 0; m < 8; ++m) {
        float v = acc[i][m] + bb[m];
        o[m] = v > 0.f ? v : 0.01f * v;
      }
      float4 o0 = {o[0], o[1], o[2], o[3]};
      float4 o1 = {o[4], o[5], o[6], o[7]};
      *(float4*)(outr + (size_t)n * 64 + d0) = o0;
      *(float4*)(outr + (size_t)n * 64 + d0 + 4) = o1;
    }
  }
}

// ---------------- launcher ----------------
extern "C" void kernel_launch(void* const* d_in, const int* in_sizes, int n_in,
                              void* d_out, int out_size, void* d_ws, size_t ws_size,
                              hipStream_t stream) {
  const float* node_score = (const float*)d_in[0];
  const float* node_repr  = (const float*)d_in[1];
  const float* rel_emb    = (const float*)d_in[2];
  const float* qs_emb     = (const float*)d_in[3];
  const float* qr_emb     = (const float*)d_in[4];
  const float* Wq         = (const float*)d_in[5];
  const float* Wk         = (const float*)d_in[6];
  const float* Wl         = (const float*)d_in[7];
  const float* bl         = (const float*)d_in[8];
  const int*   edges      = (const int*)d_in[9];

  float* out_score = (float*)d_out;                 // [200000]
  float* out_repr  = out_score + NNODES;            // [200000 x 64]; doubles as agg

  float* ws = (float*)d_ws;
  size_t o = 0;
  float* Nm      = ws + o; o += 128 * 128;
  float* alpha   = ws + o; o += NQ * 128;
  float* beta    = ws + o; o += NQ * 128;
  float* cv      = ws + o; o += NQ;
  float* exl     = ws + o; o += NE;                 // logits, then exp(l-m)
  unsigned* segmax = (unsigned*)(ws + o); o += NNODES;
  float* segsum  = ws + o; o += NNODES;
  int* sel       = (int*)(ws + o); o += NSEL;
  int* flag      = (int*)(ws + o); o += NNODES;

  hipMemsetAsync(segmax, 0, NNODES * sizeof(unsigned), stream);   // key(x) > 0 for all finite x
  hipMemsetAsync(segsum, 0, NNODES * sizeof(float), stream);
  hipMemsetAsync(flag, 0, NNODES * sizeof(int), stream);
  hipMemsetAsync(out_score, 0, NNODES * sizeof(float), stream);

  k_nmat<<<64, 256, 0, stream>>>(Wq, Wk, Nm);
  k_query<<<NQ, 256, 0, stream>>>(Wq, Wk, qs_emb, qr_emb, alpha, beta, cv);
  k_logits<<<NE / 64, 256, 0, stream>>>(node_repr, rel_emb, edges, Nm, alpha, beta, cv, exl);
  k_segmax<<<NE / 256, 256, 0, stream>>>(exl, edges, segmax);
  k_exsum<<<NE / 256, 256, 0, stream>>>(exl, edges, segmax, segsum);
  k_topk<<<NQ, 256, 0, stream>>>(exl, segsum, edges, node_score, sel, flag, out_score, out_repr);
  k_scatter<<<NSEL / 4, 256, 0, stream>>>(sel, edges, exl, segsum, node_repr, out_repr);
  k_final<<<(NNODES + FN - 1) / FN, FN, 0, stream>>>(node_repr, out_repr, flag, Wl, bl, out_repr);
}

// Round 3
// 192.488 us; speedup vs baseline: 1.1598x; 1.0857x over previous
//
#include <hip/hip_runtime.h>

#define NNODES 200000
#define NQ     128
#define EPQ    1024
#define NE     (NQ*EPQ)
#define TOPK   128
#define NSEL   (NQ*TOPK)

// ---------------- helpers ----------------
__device__ __forceinline__ unsigned fkey(float f) {
  unsigned u = __float_as_uint(f);
  return (u & 0x80000000u) ? ~u : (u | 0x80000000u);
}
__device__ __forceinline__ float fdecode(unsigned k) {
  unsigned u = (k & 0x80000000u) ? (k ^ 0x80000000u) : ~k;
  return __uint_as_float(u);
}
__device__ __forceinline__ void fmarow(float* a, float x, const float4 n0, const float4 n1) {
  a[0] = fmaf(x, n0.x, a[0]); a[1] = fmaf(x, n0.y, a[1]);
  a[2] = fmaf(x, n0.z, a[2]); a[3] = fmaf(x, n0.w, a[3]);
  a[4] = fmaf(x, n1.x, a[4]); a[5] = fmaf(x, n1.y, a[5]);
  a[6] = fmaf(x, n1.z, a[6]); a[7] = fmaf(x, n1.w, a[7]);
}

typedef const __attribute__((address_space(1))) void* gas_ptr;
typedef __attribute__((address_space(3))) void* las_ptr;
__device__ __forceinline__ void gload16(const void* g, void* l) {
  __builtin_amdgcn_global_load_lds((gas_ptr)g, (las_ptr)l, 16, 0, 0);
}

// permuted within-row index for Nm: lane kg reads k=8kg..8kg+7 via two
// conflict-free ds_read_b128 at byte kg*16 and 256+kg*16 of the 512B row.
__device__ __forceinline__ int nperm(int k) {
  const int q = k >> 2, p = k & 3;
  return (q & 1) * 64 + (q >> 1) * 4 + p;
}

// ---------------- init: zero the node tables (1 launch instead of 4 memsets) --
__global__ __launch_bounds__(256) void k_init(unsigned* __restrict__ segmax,
                                              float* __restrict__ segsum,
                                              int* __restrict__ flag,
                                              float* __restrict__ outs) {
  const int i = blockIdx.x * 256 + threadIdx.x;
  if (i < NNODES) { segmax[i] = 0u; segsum[i] = 0.f; flag[i] = 0; outs[i] = 0.f; }
}

// ---------------- N = WqL^T * WkL  (128x128, permuted row layout) ----------------
// 128 blocks (one per j), 256 threads = 128 k x 2 i-halves; deterministic LDS combine.
__global__ __launch_bounds__(256) void k_nmat(const float* __restrict__ Wq,
                                              const float* __restrict__ Wk,
                                              float* __restrict__ Nm) {
  __shared__ float ph[128];
  const int j = blockIdx.x;
  const int k = threadIdx.x & 127;
  const int ih = threadIdx.x >> 7;
  const int i0 = ih * 128;
  float a0 = 0.f, a1 = 0.f, a2 = 0.f, a3 = 0.f;
  for (int i = i0; i < i0 + 128; i += 4) {
    a0 = fmaf(Wq[(i + 0) * 256 + j], Wk[(i + 0) * 256 + k], a0);
    a1 = fmaf(Wq[(i + 1) * 256 + j], Wk[(i + 1) * 256 + k], a1);
    a2 = fmaf(Wq[(i + 2) * 256 + j], Wk[(i + 2) * 256 + k], a2);
    a3 = fmaf(Wq[(i + 3) * 256 + j], Wk[(i + 3) * 256 + k], a3);
  }
  const float p = (a0 + a1) + (a2 + a3);
  if (ih == 0) ph[k] = p;
  __syncthreads();
  if (ih == 1) Nm[j * 128 + nperm(k)] = ph[k] + p;
}

// ---------------- per-query alpha/beta/c ----------------
__global__ __launch_bounds__(256) void k_query(const float* __restrict__ Wq,
                                               const float* __restrict__ Wk,
                                               const float* __restrict__ qs_emb,
                                               const float* __restrict__ qr_emb,
                                               float* __restrict__ alpha,
                                               float* __restrict__ beta,
                                               float* __restrict__ cv) {
  __shared__ float sq[128];
  __shared__ float u[256], v[256];
  const int q = blockIdx.x, t = threadIdx.x;
  if (t < 64) sq[t] = qs_emb[q * 64 + t];
  else if (t < 128) sq[t] = qr_emb[q * 64 + (t - 64)];
  __syncthreads();
  {
    const float4* wq4 = (const float4*)(Wq + t * 256 + 128);
    const float4* wk4 = (const float4*)(Wk + t * 256 + 128);
    const float4* sq4 = (const float4*)sq;
    float uu = 0.f, vv = 0.f;
#pragma unroll 8
    for (int j = 0; j < 32; ++j) {
      const float4 a = wq4[j], b = wk4[j], s = sq4[j];
      uu = fmaf(a.x, s.x, fmaf(a.y, s.y, fmaf(a.z, s.z, fmaf(a.w, s.w, uu))));
      vv = fmaf(b.x, s.x, fmaf(b.y, s.y, fmaf(b.z, s.z, fmaf(b.w, s.w, vv))));
    }
    u[t] = uu; v[t] = vv;
  }
  __syncthreads();
  if (t < 128) {
    float a0 = 0.f, a1 = 0.f, a2 = 0.f, a3 = 0.f;
    for (int i = 0; i < 256; i += 4) {
      a0 = fmaf(Wq[(i + 0) * 256 + t], v[i + 0], a0);
      a1 = fmaf(Wq[(i + 1) * 256 + t], v[i + 1], a1);
      a2 = fmaf(Wq[(i + 2) * 256 + t], v[i + 2], a2);
      a3 = fmaf(Wq[(i + 3) * 256 + t], v[i + 3], a3);
    }
    alpha[q * 128 + t] = (a0 + a1) + (a2 + a3);
  } else {
    const int k = t - 128;
    float b0 = 0.f, b1 = 0.f, b2 = 0.f, b3 = 0.f;
    for (int i = 0; i < 256; i += 4) {
      b0 = fmaf(u[i + 0], Wk[(i + 0) * 256 + k], b0);
      b1 = fmaf(u[i + 1], Wk[(i + 1) * 256 + k], b1);
      b2 = fmaf(u[i + 2], Wk[(i + 2) * 256 + k], b2);
      b3 = fmaf(u[i + 3], Wk[(i + 3) * 256 + k], b3);
    }
    beta[q * 128 + k] = (b0 + b1) + (b2 + b3);
  }
  __syncthreads();
  if (t < 64) {
    float c = u[t] * v[t] + u[t + 64] * v[t + 64] + u[t + 128] * v[t + 128] + u[t + 192] * v[t + 192];
    c += __shfl_xor(c, 32, 64);
    c += __shfl_xor(c, 16, 64);
    c += __shfl_xor(c, 8, 64);
    c += __shfl_xor(c, 4, 64);
    c += __shfl_xor(c, 2, 64);
    c += __shfl_xor(c, 1, 64);
    if (t == 0) cv[q] = c;
  }
}

// ---------------- edge logits: logit = x^T N y + a.x + b.y + c ----------------
// 64 edges/block, 128 threads, thread tile = 8 edges x 8 k (16 FMA / LDS instr).
// N streamed through LDS in 8 double-buffered chunks of 16 rows (8KB).
__global__ __launch_bounds__(128) void k_logits(
    const float* __restrict__ repr, const float* __restrict__ rel,
    const int* __restrict__ edges, const float* __restrict__ Nm,
    const float* __restrict__ alpha, const float* __restrict__ beta,
    const float* __restrict__ cv, float* __restrict__ logits) {
  __shared__ float Xt[128][64];      // rows 0..63 = repr[src] (j), 64..127 = rel
  __shared__ float Nb[2][2048];      // double-buffered N chunk (16 rows x 128 f, permuted)
  __shared__ float sA[128], sB[128];
  __shared__ int sSrc[64], sDst[64];
  const int t = threadIdx.x;
  const int e0 = blockIdx.x * 64;
  const int q = e0 >> 10;

  // issue chunk 0 N loads first (overlap with X staging below)
  {
    const char* g = (const char*)Nm + (size_t)t * 16;
    char* l = (char*)&Nb[0][0] + (t >> 6) * 1024;
#pragma unroll
    for (int r = 0; r < 4; ++r) gload16(g + r * 2048, l + r * 2048);
  }

  // stage X: thread t<64 stages repr[src] row el=t into rows 0..63,
  //          t>=64 stages rel row el into rows 64..127.
  {
    const int el = t & 63;
    const int half = t >> 6;
    const int e = e0 + el;
    const float4* p;
    if (half == 0) {
      const int src = edges[e * 8 + 6];
      sSrc[el] = src;
      sDst[el] = edges[e * 8 + 7];
      p = (const float4*)(repr + (size_t)src * 64);
    } else {
      p = (const float4*)(rel + (size_t)e * 64);
    }
    const int jbase = half * 64;
#pragma unroll
    for (int i = 0; i < 16; ++i) {
      const float4 v4 = p[i];
      const int j = jbase + i * 4;
      Xt[j + 0][el] = v4.x; Xt[j + 1][el] = v4.y; Xt[j + 2][el] = v4.z; Xt[j + 3][el] = v4.w;
    }
    sA[t] = alpha[q * 128 + t];
    sB[t] = beta[q * 128 + t];
  }
  __syncthreads();   // drains vmcnt: chunk 0 resident, X tile resident

  const int kg = t & 15, eg = t >> 4;     // eg 0..7
  const int k0 = kg * 8, eb = eg * 8;
  const int kf = kg * 4;                  // float offset within permuted 128-f row
  float acc[8][8];
#pragma unroll
  for (int i = 0; i < 8; ++i)
#pragma unroll
    for (int m = 0; m < 8; ++m) acc[i][m] = 0.f;

  for (int ch = 0; ch < 8; ++ch) {
    if (ch < 7) {
      const char* g = (const char*)Nm + (ch + 1) * 8192 + (size_t)t * 16;
      char* l = (char*)&Nb[(ch + 1) & 1][0] + (t >> 6) * 1024;
#pragma unroll
      for (int r = 0; r < 4; ++r) gload16(g + r * 2048, l + r * 2048);
    }
    const float* __restrict__ Xrow = &Xt[ch * 16][0];
    const float* __restrict__ Nrow = &Nb[ch & 1][0];
#pragma unroll 4
    for (int jl = 0; jl < 16; ++jl) {
      const float4 n0 = *(const float4*)(Nrow + jl * 128 + kf);
      const float4 n1 = *(const float4*)(Nrow + jl * 128 + 64 + kf);
      const float4 x0 = *(const float4*)(Xrow + jl * 64 + eb);
      const float4 x1 = *(const float4*)(Xrow + jl * 64 + eb + 4);
      fmarow(acc[0], x0.x, n0, n1);
      fmarow(acc[1], x0.y, n0, n1);
      fmarow(acc[2], x0.z, n0, n1);
      fmarow(acc[3], x0.w, n0, n1);
      fmarow(acc[4], x1.x, n0, n1);
      fmarow(acc[5], x1.y, n0, n1);
      fmarow(acc[6], x1.z, n0, n1);
      fmarow(acc[7], x1.w, n0, n1);
    }
    __syncthreads();   // next chunk resident; orders buffer reuse
  }

  float aA[8], aB[8];
#pragma unroll
  for (int m = 0; m < 8; ++m) { aA[m] = sA[k0 + m]; aB[m] = sB[k0 + m]; }

  float part[8];
#pragma unroll
  for (int i = 0; i < 8; ++i) {
    const int el = eb + i;
    const int e = e0 + el;
    const float* xp;
    const float* yp;
    if (k0 < 64) {
      xp = repr + (size_t)sSrc[el] * 64 + k0;
      yp = repr + (size_t)sDst[el] * 64 + k0;
    } else {
      xp = rel + (size_t)e * 64 + (k0 - 64);
      yp = xp;
    }
    const float4 x0 = *(const float4*)xp;
    const float4 x1 = *(const float4*)(xp + 4);
    const float4 y0 = *(const float4*)yp;
    const float4 y1 = *(const float4*)(yp + 4);
    const float xs[8] = {x0.x, x0.y, x0.z, x0.w, x1.x, x1.y, x1.z, x1.w};
    const float ys[8] = {y0.x, y0.y, y0.z, y0.w, y1.x, y1.y, y1.z, y1.w};
    float p = 0.f;
#pragma unroll
    for (int m = 0; m < 8; ++m)
      p += (acc[i][m] + aB[m]) * ys[m] + aA[m] * xs[m];
    part[i] = p;
  }
#pragma unroll
  for (int i = 0; i < 8; ++i) {
    float p = part[i];
    p += __shfl_xor(p, 8, 64);
    p += __shfl_xor(p, 4, 64);
    p += __shfl_xor(p, 2, 64);
    p += __shfl_xor(p, 1, 64);
    part[i] = p;
  }
  if (kg == 0) {
    const float cq = cv[q];
#pragma unroll
    for (int i = 0; i < 8; ++i) logits[e0 + eb + i] = part[i] + cq;
  }
}

// ---------------- segment softmax (by src) ----------------
__global__ __launch_bounds__(256) void k_segmax(const float* __restrict__ logits,
                                                const int* __restrict__ edges,
                                                unsigned* __restrict__ segmax) {
  const int e = blockIdx.x * 256 + threadIdx.x;
  const int src = edges[e * 8 + 6];
  atomicMax(&segmax[src], fkey(logits[e]));
}

__global__ __launch_bounds__(256) void k_exsum(float* __restrict__ logits,
                                               const int* __restrict__ edges,
                                               const unsigned* __restrict__ segmax,
                                               float* __restrict__ segsum) {
  const int e = blockIdx.x * 256 + threadIdx.x;
  const int src = edges[e * 8 + 6];
  const float m = fdecode(segmax[src]);
  const float ex = expf(logits[e] - m);
  logits[e] = ex;                       // in-place: now holds exp(l - m)
  atomicAdd(&segsum[src], ex);
}

// ---------------- per-query top-128: 4-pass radix select (exact tie-break) -----
__global__ __launch_bounds__(256) void k_topk(const float* __restrict__ ex,
                                              const float* __restrict__ segsum,
                                              const int* __restrict__ edges,
                                              const float* __restrict__ node_score,
                                              int* __restrict__ sel,
                                              int* __restrict__ flag,
                                              float* __restrict__ out_score,
                                              float* agg) {
  __shared__ unsigned keys[1024];
  __shared__ int hist[256];
  __shared__ int selEl[128];
  __shared__ int eqIdx[32];
  __shared__ int sB0, sRank, sCnt, sEq;
  const int q = blockIdx.x, t = threadIdx.x;
  for (int i = t; i < 1024; i += 256) {
    const int e = q * 1024 + i;
    const int src = edges[e * 8 + 6];
    const float ts = (ex[e] / segsum[src]) * node_score[src];
    keys[i] = fkey(ts);
  }
  unsigned prefix = 0, pmask = 0;
  int rank = 128;                 // rank-th largest among candidates
  __syncthreads();
#pragma unroll
  for (int pass = 0; pass < 4; ++pass) {
    const int shift = 24 - 8 * pass;
    hist[t] = 0;
    __syncthreads();
    for (int i = t; i < 1024; i += 256) {
      const unsigned k = keys[i];
      if ((k & pmask) == prefix) atomicAdd(&hist[(k >> shift) & 255], 1);
    }
    __syncthreads();
    if (t < 64) {
      const int h0 = hist[4 * t], h1 = hist[4 * t + 1], h2 = hist[4 * t + 2], h3 = hist[4 * t + 3];
      const int s4 = h0 + h1 + h2 + h3;
      int S = s4;
      for (int d = 1; d < 64; d <<= 1) {
        const int o = __shfl_down(S, d, 64);
        if (t + d < 64) S += o;
      }
      const int Snext = S - s4;          // suffix sum excluding this lane's bins
      if (S >= rank && Snext < rank) {   // exactly one lane crosses
        int r = rank - Snext;            // r-th from top within these 4 bins
        int b;
        if (r <= h3) b = 3;
        else if (r <= h3 + h2) { b = 2; r -= h3; }
        else if (r <= h3 + h2 + h1) { b = 1; r -= h3 + h2; }
        else { b = 0; r -= h3 + h2 + h1; }
        sB0 = 4 * t + b; sRank = r;
      }
    }
    __syncthreads();
    prefix |= ((unsigned)sB0) << shift;
    pmask |= 0xFFu << shift;
    rank = sRank;
    __syncthreads();
  }
  const unsigned thr = prefix;           // 128th-largest key; take `rank` of == thr
  if (t == 0) { sCnt = 0; sEq = 0; }
  __syncthreads();
  for (int i = t; i < 1024; i += 256) {
    const unsigned k = keys[i];
    if (k > thr) { const int s = atomicAdd(&sCnt, 1); selEl[s] = i; }
    else if (k == thr) { const int j = atomicAdd(&sEq, 1); if (j < 32) eqIdx[j] = i; }
  }
  __syncthreads();
  if (t == 0) {
    int n = sEq; if (n > 32) n = 32;
    for (int a = 1; a < n; ++a) {        // ascending index sort (ties: smallest idx)
      const int v2 = eqIdx[a]; int b = a - 1;
      while (b >= 0 && eqIdx[b] > v2) { eqIdx[b + 1] = eqIdx[b]; --b; }
      eqIdx[b + 1] = v2;
    }
    for (int r2 = 0; r2 < rank; ++r2) selEl[sCnt + r2] = eqIdx[r2];
  }
  __syncthreads();
  if (t < 128) {
    const int el = selEl[t];
    const int e = q * 1024 + el;
    sel[q * 128 + t] = e;
    const int src = edges[e * 8 + 6];
    const int dst = edges[e * 8 + 7];
    const float soft = ex[e] / segsum[src];
    atomicAdd(&out_score[dst], soft * node_score[src]);
    flag[src] = 1;
  }
  __syncthreads();
  // zero agg rows for selected src (all zeroing precedes all adds: next kernel)
  for (int i = t; i < 128 * 64; i += 256) {
    const int s = i >> 6, d = i & 63;
    const int e = q * 1024 + selEl[s];
    const int src = edges[e * 8 + 6];
    agg[(size_t)src * 64 + d] = 0.f;
  }
}

// ---------------- scatter: agg[src] += soft * repr[dst] ----------------
__global__ __launch_bounds__(256) void k_scatter(const int* __restrict__ sel,
                                                 const int* __restrict__ edges,
                                                 const float* __restrict__ ex,
                                                 const float* __restrict__ segsum,
                                                 const float* __restrict__ repr,
                                                 float* agg) {
  const int i = blockIdx.x * 4 + (threadIdx.x >> 6);   // selected slot
  const int d = threadIdx.x & 63;
  const int e = sel[i];
  const int src = edges[e * 8 + 6];
  const int dst = edges[e * 8 + 7];
  const float soft = ex[e] / segsum[src];
  atomicAdd(&agg[(size_t)src * 64 + d], soft * repr[(size_t)dst * 64 + d]);
}

// ---------------- final: out = leakyrelu(upd @ W_lin + b) ----------------
#define FN 192
__global__ __launch_bounds__(192) void k_final(const float* __restrict__ repr,
                                               const float* agg,      // aliases outr
                                               const int* __restrict__ flag,
                                               const float* __restrict__ Wl,
                                               const float* __restrict__ bl,
                                               float* outr) {
  __shared__ float Ut[64][FN];
  __shared__ float W[64][64];
  __shared__ float bs[64];
  const int t = threadIdx.x;
  const int n0blk = blockIdx.x * FN;
  for (int i = t; i < 4096; i += FN) W[i >> 6][i & 63] = Wl[i];
  if (t < 64) bs[t] = bl[t];
  {
    const int n = n0blk + t;
    const bool ok = n < NNODES;
    const float* rowp = repr;
    if (ok) rowp = (flag[n] ? agg : repr) + (size_t)n * 64;
#pragma unroll
    for (int i = 0; i < 16; ++i) {
      float4 v4 = ok ? ((const float4*)rowp)[i] : float4{0.f, 0.f, 0.f, 0.f};
      const int c = i * 4;
      Ut[c + 0][t] = v4.x; Ut[c + 1][t] = v4.y; Ut[c + 2][t] = v4.z; Ut[c + 3][t] = v4.w;
    }
  }
  __syncthreads();
  const int dg = t & 7, ng = t >> 3;       // 8 d-groups x 24 n-groups
  const int d0 = dg * 8, nb = ng * 8;
  float acc[8][8];
#pragma unroll
  for (int i = 0; i < 8; ++i)
#pragma unroll
    for (int m = 0; m < 8; ++m) acc[i][m] = 0.f;
#pragma unroll 2
  for (int c = 0; c < 64; ++c) {
    const float4 w0 = *(const float4*)&W[c][d0];
    const float4 w1 = *(const float4*)&W[c][d0 + 4];
    const float4 u0 = *(const float4*)&Ut[c][nb];
    const float4 u1 = *(const float4*)&Ut[c][nb + 4];
    fmarow(acc[0], u0.x, w0, w1);
    fmarow(acc[1], u0.y, w0, w1);
    fmarow(acc[2], u0.z, w0, w1);
    fmarow(acc[3], u0.w, w0, w1);
    fmarow(acc[4], u1.x, w0, w1);
    fmarow(acc[5], u1.y, w0, w1);
    fmarow(acc[6], u1.z, w0, w1);
    fmarow(acc[7], u1.w, w0, w1);
  }
  float bb[8];
#pragma unroll
  for (int m = 0; m < 8; ++m) bb[m] = bs[d0 + m];
#pragma unroll
  for (int i = 0; i < 8; ++i) {
    const int n = n0blk + nb + i;
    if (n < NNODES) {
      float o[8];
#pragma unroll
      for (int m = 0; m < 8; ++m) {
        float v = acc[i][m] + bb[m];
        o[m] = v > 0.f ? v : 0.01f * v;
      }
      float4 o0 = {o[0], o[1], o[2], o[3]};
      float4 o1 = {o[4], o[5], o[6], o[7]};
      *(float4*)(outr + (size_t)n * 64 + d0) = o0;
      *(float4*)(outr + (size_t)n * 64 + d0 + 4) = o1;
    }
  }
}

// ---------------- launcher ----------------
extern "C" void kernel_launch(void* const* d_in, const int* in_sizes, int n_in,
                              void* d_out, int out_size, void* d_ws, size_t ws_size,
                              hipStream_t stream) {
  const float* node_score = (const float*)d_in[0];
  const float* node_repr  = (const float*)d_in[1];
  const float* rel_emb    = (const float*)d_in[2];
  const float* qs_emb     = (const float*)d_in[3];
  const float* qr_emb     = (const float*)d_in[4];
  const float* Wq         = (const float*)d_in[5];
  const float* Wk         = (const float*)d_in[6];
  const float* Wl         = (const float*)d_in[7];
  const float* bl         = (const float*)d_in[8];
  const int*   edges      = (const int*)d_in[9];

  float* out_score = (float*)d_out;                 // [200000]
  float* out_repr  = out_score + NNODES;            // [200000 x 64]; doubles as agg

  float* ws = (float*)d_ws;
  size_t o = 0;
  float* Nm      = ws + o; o += 128 * 128;
  float* alpha   = ws + o; o += NQ * 128;
  float* beta    = ws + o; o += NQ * 128;
  float* cv      = ws + o; o += NQ;
  float* exl     = ws + o; o += NE;                 // logits, then exp(l-m)
  unsigned* segmax = (unsigned*)(ws + o); o += NNODES;
  float* segsum  = ws + o; o += NNODES;
  int* sel       = (int*)(ws + o); o += NSEL;
  int* flag      = (int*)(ws + o); o += NNODES;

  k_init<<<(NNODES + 255) / 256, 256, 0, stream>>>(segmax, segsum, flag, out_score);
  k_nmat<<<128, 256, 0, stream>>>(Wq, Wk, Nm);
  k_query<<<NQ, 256, 0, stream>>>(Wq, Wk, qs_emb, qr_emb, alpha, beta, cv);
  k_logits<<<NE / 64, 128, 0, stream>>>(node_repr, rel_emb, edges, Nm, alpha, beta, cv, exl);
  k_segmax<<<NE / 256, 256, 0, stream>>>(exl, edges, segmax);
  k_exsum<<<NE / 256, 256, 0, stream>>>(exl, edges, segmax, segsum);
  k_topk<<<NQ, 256, 0, stream>>>(exl, segsum, edges, node_score, sel, flag, out_score, out_repr);
  k_scatter<<<NSEL / 4, 256, 0, stream>>>(sel, edges, exl, segsum, node_repr, out_repr);
  k_final<<<(NNODES + FN - 1) / FN, FN, 0, stream>>>(node_repr, out_repr, flag, Wl, bl, out_repr);
}

// Round 4
// 185.376 us; speedup vs baseline: 1.2043x; 1.0384x over previous
//
#include <hip/hip_runtime.h>

#define NNODES 200000
#define NQ     128
#define EPQ    1024
#define NE     (NQ*EPQ)
#define TOPK   128
#define NSEL   (NQ*TOPK)

// ---------------- helpers ----------------
__device__ __forceinline__ unsigned fkey(float f) {
  unsigned u = __float_as_uint(f);
  return (u & 0x80000000u) ? ~u : (u | 0x80000000u);
}
__device__ __forceinline__ float fdecode(unsigned k) {
  unsigned u = (k & 0x80000000u) ? (k ^ 0x80000000u) : ~k;
  return __uint_as_float(u);
}
__device__ __forceinline__ void fmarow(float* a, float x, const float4 n0, const float4 n1) {
  a[0] = fmaf(x, n0.x, a[0]); a[1] = fmaf(x, n0.y, a[1]);
  a[2] = fmaf(x, n0.z, a[2]); a[3] = fmaf(x, n0.w, a[3]);
  a[4] = fmaf(x, n1.x, a[4]); a[5] = fmaf(x, n1.y, a[5]);
  a[6] = fmaf(x, n1.z, a[6]); a[7] = fmaf(x, n1.w, a[7]);
}

typedef const __attribute__((address_space(1))) void* gas_ptr;
typedef __attribute__((address_space(3))) void* las_ptr;
__device__ __forceinline__ void gload16(const void* g, void* l) {
  __builtin_amdgcn_global_load_lds((gas_ptr)g, (las_ptr)l, 16, 0, 0);
}

// permuted within-row index for Nm: lane kg reads k=8kg..8kg+7 via two
// conflict-free ds_read_b128 at byte kg*16 and 256+kg*16 of the 512B row.
__device__ __forceinline__ int nperm(int k) {
  const int q = k >> 2, p = k & 3;
  return (q & 1) * 64 + (q >> 1) * 4 + p;
}

// ---------------- init: zero the node tables ----------------
__global__ __launch_bounds__(256) void k_init(unsigned* __restrict__ segmax,
                                              float* __restrict__ segsum,
                                              int* __restrict__ flag,
                                              float* __restrict__ outs) {
  const int i = blockIdx.x * 256 + threadIdx.x;
  if (i < NNODES) { segmax[i] = 0u; segsum[i] = 0.f; flag[i] = 0; outs[i] = 0.f; }
}

// ---------------- N = WqL^T * WkL  (128x128, permuted row layout) ----------------
__global__ __launch_bounds__(256) void k_nmat(const float* __restrict__ Wq,
                                              const float* __restrict__ Wk,
                                              float* __restrict__ Nm) {
  __shared__ float ph[128];
  const int j = blockIdx.x;
  const int k = threadIdx.x & 127;
  const int ih = threadIdx.x >> 7;
  const int i0 = ih * 128;
  float a0 = 0.f, a1 = 0.f, a2 = 0.f, a3 = 0.f;
  for (int i = i0; i < i0 + 128; i += 4) {
    a0 = fmaf(Wq[(i + 0) * 256 + j], Wk[(i + 0) * 256 + k], a0);
    a1 = fmaf(Wq[(i + 1) * 256 + j], Wk[(i + 1) * 256 + k], a1);
    a2 = fmaf(Wq[(i + 2) * 256 + j], Wk[(i + 2) * 256 + k], a2);
    a3 = fmaf(Wq[(i + 3) * 256 + j], Wk[(i + 3) * 256 + k], a3);
  }
  const float p = (a0 + a1) + (a2 + a3);
  if (ih == 0) ph[k] = p;
  __syncthreads();
  if (ih == 1) Nm[j * 128 + nperm(k)] = ph[k] + p;
}

// ---------------- per-query alpha/beta/c ----------------
__global__ __launch_bounds__(256) void k_query(const float* __restrict__ Wq,
                                               const float* __restrict__ Wk,
                                               const float* __restrict__ qs_emb,
                                               const float* __restrict__ qr_emb,
                                               float* __restrict__ alpha,
                                               float* __restrict__ beta,
                                               float* __restrict__ cv) {
  __shared__ float sq[128];
  __shared__ float u[256], v[256];
  const int q = blockIdx.x, t = threadIdx.x;
  if (t < 64) sq[t] = qs_emb[q * 64 + t];
  else if (t < 128) sq[t] = qr_emb[q * 64 + (t - 64)];
  __syncthreads();
  {
    const float4* wq4 = (const float4*)(Wq + t * 256 + 128);
    const float4* wk4 = (const float4*)(Wk + t * 256 + 128);
    const float4* sq4 = (const float4*)sq;
    float uu = 0.f, vv = 0.f;
#pragma unroll 8
    for (int j = 0; j < 32; ++j) {
      const float4 a = wq4[j], b = wk4[j], s = sq4[j];
      uu = fmaf(a.x, s.x, fmaf(a.y, s.y, fmaf(a.z, s.z, fmaf(a.w, s.w, uu))));
      vv = fmaf(b.x, s.x, fmaf(b.y, s.y, fmaf(b.z, s.z, fmaf(b.w, s.w, vv))));
    }
    u[t] = uu; v[t] = vv;
  }
  __syncthreads();
  if (t < 128) {
    float a0 = 0.f, a1 = 0.f, a2 = 0.f, a3 = 0.f;
    for (int i = 0; i < 256; i += 4) {
      a0 = fmaf(Wq[(i + 0) * 256 + t], v[i + 0], a0);
      a1 = fmaf(Wq[(i + 1) * 256 + t], v[i + 1], a1);
      a2 = fmaf(Wq[(i + 2) * 256 + t], v[i + 2], a2);
      a3 = fmaf(Wq[(i + 3) * 256 + t], v[i + 3], a3);
    }
    alpha[q * 128 + t] = (a0 + a1) + (a2 + a3);
  } else {
    const int k = t - 128;
    float b0 = 0.f, b1 = 0.f, b2 = 0.f, b3 = 0.f;
    for (int i = 0; i < 256; i += 4) {
      b0 = fmaf(u[i + 0], Wk[(i + 0) * 256 + k], b0);
      b1 = fmaf(u[i + 1], Wk[(i + 1) * 256 + k], b1);
      b2 = fmaf(u[i + 2], Wk[(i + 2) * 256 + k], b2);
      b3 = fmaf(u[i + 3], Wk[(i + 3) * 256 + k], b3);
    }
    beta[q * 128 + k] = (b0 + b1) + (b2 + b3);
  }
  __syncthreads();
  if (t < 64) {
    float c = u[t] * v[t] + u[t + 64] * v[t + 64] + u[t + 128] * v[t + 128] + u[t + 192] * v[t + 192];
    c += __shfl_xor(c, 32, 64);
    c += __shfl_xor(c, 16, 64);
    c += __shfl_xor(c, 8, 64);
    c += __shfl_xor(c, 4, 64);
    c += __shfl_xor(c, 2, 64);
    c += __shfl_xor(c, 1, 64);
    if (t == 0) cv[q] = c;
  }
}

// ---------------- edge logits: logit = x^T N y + a.x + b.y + c ----------------
// 128 edges/block, 512 threads, thread tile = 4 edges x 8 k.
// Full N (64KB) + full X tile (64KB) resident in LDS; ONE barrier, then 128
// straight j-iterations (no per-chunk vmcnt/barrier drains).
__global__ __launch_bounds__(512, 1) void k_logits(
    const float* __restrict__ repr, const float* __restrict__ rel,
    const int* __restrict__ edges, const float* __restrict__ Nm,
    const float* __restrict__ alpha, const float* __restrict__ beta,
    const float* __restrict__ cv, float* __restrict__ logits) {
  __shared__ float Nl[128 * 128];    // full permuted N
  __shared__ float Xt[128][128];     // j-major X tile: rows 0..63 repr[src], 64..127 rel
  __shared__ float sA[128], sB[128];
  __shared__ int sSrc[128], sDst[128];
  const int t = threadIdx.x;
  const int e0 = blockIdx.x * 128;
  const int q = e0 >> 10;

  // stage all of N via global_load_lds (8 rounds x 512 lanes x 16B = 64KB)
  {
    const char* g = (const char*)Nm + (size_t)t * 16;
    char* l = (char*)Nl + (size_t)t * 16;
#pragma unroll
    for (int r = 0; r < 8; ++r) gload16(g + r * 8192, l + r * 8192);
  }

  // stage X transposed: threads 0..127 -> repr[src] rows (j 0..63),
  //                     threads 128..255 -> rel rows (j 64..127)
  if (t < 256) {
    const int el = t & 127;
    const int half = t >> 7;
    const int e = e0 + el;
    const float4* p;
    if (half == 0) {
      const int src = edges[e * 8 + 6];
      sSrc[el] = src;
      sDst[el] = edges[e * 8 + 7];
      p = (const float4*)(repr + (size_t)src * 64);
    } else {
      p = (const float4*)(rel + (size_t)e * 64);
    }
    const int jb = half * 64;
#pragma unroll
    for (int i = 0; i < 16; ++i) {
      const float4 v4 = p[i];
      const int j = jb + i * 4;
      Xt[j + 0][el] = v4.x; Xt[j + 1][el] = v4.y; Xt[j + 2][el] = v4.z; Xt[j + 3][el] = v4.w;
    }
  } else if (t < 384) {
    sA[t - 256] = alpha[q * 128 + (t - 256)];
  } else {
    sB[t - 384] = beta[q * 128 + (t - 384)];
  }
  __syncthreads();   // one-time drain: N + X resident

  const int kg = t & 15, eg = t >> 4;     // eg 0..31
  const int k0 = kg * 8, eb = eg * 4;
  const int kf = kg * 4;                  // float offset within permuted 128-f row
  float acc[4][8];
#pragma unroll
  for (int i = 0; i < 4; ++i)
#pragma unroll
    for (int m = 0; m < 8; ++m) acc[i][m] = 0.f;

#pragma unroll 4
  for (int j = 0; j < 128; ++j) {
    const float* __restrict__ Nrow = Nl + j * 128;
    const float4 n0 = *(const float4*)(Nrow + kf);
    const float4 n1 = *(const float4*)(Nrow + 64 + kf);
    const float4 xv = *(const float4*)(&Xt[j][eb]);
    fmarow(acc[0], xv.x, n0, n1);
    fmarow(acc[1], xv.y, n0, n1);
    fmarow(acc[2], xv.z, n0, n1);
    fmarow(acc[3], xv.w, n0, n1);
  }

  float aA[8], aB[8];
#pragma unroll
  for (int m = 0; m < 8; ++m) { aA[m] = sA[k0 + m]; aB[m] = sB[k0 + m]; }

  float part[4];
#pragma unroll
  for (int i = 0; i < 4; ++i) {
    const int el = eb + i;
    const int e = e0 + el;
    const float* xp;
    const float* yp;
    if (k0 < 64) {
      xp = repr + (size_t)sSrc[el] * 64 + k0;
      yp = repr + (size_t)sDst[el] * 64 + k0;
    } else {
      xp = rel + (size_t)e * 64 + (k0 - 64);
      yp = xp;
    }
    const float4 x0 = *(const float4*)xp;
    const float4 x1 = *(const float4*)(xp + 4);
    const float4 y0 = *(const float4*)yp;
    const float4 y1 = *(const float4*)(yp + 4);
    const float xs[8] = {x0.x, x0.y, x0.z, x0.w, x1.x, x1.y, x1.z, x1.w};
    const float ys[8] = {y0.x, y0.y, y0.z, y0.w, y1.x, y1.y, y1.z, y1.w};
    float p = 0.f;
#pragma unroll
    for (int m = 0; m < 8; ++m)
      p += (acc[i][m] + aB[m]) * ys[m] + aA[m] * xs[m];
    part[i] = p;
  }
#pragma unroll
  for (int i = 0; i < 4; ++i) {
    float p = part[i];
    p += __shfl_xor(p, 8, 64);
    p += __shfl_xor(p, 4, 64);
    p += __shfl_xor(p, 2, 64);
    p += __shfl_xor(p, 1, 64);
    part[i] = p;
  }
  if (kg == 0) {
    const float cq = cv[q];
#pragma unroll
    for (int i = 0; i < 4; ++i) logits[e0 + eb + i] = part[i] + cq;
  }
}

// ---------------- segment softmax (by src) ----------------
__global__ __launch_bounds__(256) void k_segmax(const float* __restrict__ logits,
                                                const int* __restrict__ edges,
                                                unsigned* __restrict__ segmax) {
  const int e = blockIdx.x * 256 + threadIdx.x;
  const int src = edges[e * 8 + 6];
  atomicMax(&segmax[src], fkey(logits[e]));
}

__global__ __launch_bounds__(256) void k_exsum(float* __restrict__ logits,
                                               const int* __restrict__ edges,
                                               const unsigned* __restrict__ segmax,
                                               float* __restrict__ segsum) {
  const int e = blockIdx.x * 256 + threadIdx.x;
  const int src = edges[e * 8 + 6];
  const float m = fdecode(segmax[src]);
  const float ex = expf(logits[e] - m);
  logits[e] = ex;                       // in-place: now holds exp(l - m)
  atomicAdd(&segsum[src], ex);
}

// ---------------- per-query top-128: 4-pass radix select (exact tie-break) -----
__global__ __launch_bounds__(256) void k_topk(const float* __restrict__ ex,
                                              const float* __restrict__ segsum,
                                              const int* __restrict__ edges,
                                              const float* __restrict__ node_score,
                                              int* __restrict__ sel,
                                              int* __restrict__ flag,
                                              float* __restrict__ out_score,
                                              float* agg) {
  __shared__ unsigned keys[1024];
  __shared__ int hist[256];
  __shared__ int selEl[128];
  __shared__ int eqIdx[32];
  __shared__ int sB0, sRank, sCnt, sEq;
  const int q = blockIdx.x, t = threadIdx.x;
  for (int i = t; i < 1024; i += 256) {
    const int e = q * 1024 + i;
    const int src = edges[e * 8 + 6];
    const float ts = (ex[e] / segsum[src]) * node_score[src];
    keys[i] = fkey(ts);
  }
  unsigned prefix = 0, pmask = 0;
  int rank = 128;                 // rank-th largest among candidates
  __syncthreads();
#pragma unroll
  for (int pass = 0; pass < 4; ++pass) {
    const int shift = 24 - 8 * pass;
    hist[t] = 0;
    __syncthreads();
    for (int i = t; i < 1024; i += 256) {
      const unsigned k = keys[i];
      if ((k & pmask) == prefix) atomicAdd(&hist[(k >> shift) & 255], 1);
    }
    __syncthreads();
    if (t < 64) {
      const int h0 = hist[4 * t], h1 = hist[4 * t + 1], h2 = hist[4 * t + 2], h3 = hist[4 * t + 3];
      const int s4 = h0 + h1 + h2 + h3;
      int S = s4;
      for (int d = 1; d < 64; d <<= 1) {
        const int o = __shfl_down(S, d, 64);
        if (t + d < 64) S += o;
      }
      const int Snext = S - s4;          // suffix sum excluding this lane's bins
      if (S >= rank && Snext < rank) {   // exactly one lane crosses
        int r = rank - Snext;            // r-th from top within these 4 bins
        int b;
        if (r <= h3) b = 3;
        else if (r <= h3 + h2) { b = 2; r -= h3; }
        else if (r <= h3 + h2 + h1) { b = 1; r -= h3 + h2; }
        else { b = 0; r -= h3 + h2 + h1; }
        sB0 = 4 * t + b; sRank = r;
      }
    }
    __syncthreads();
    prefix |= ((unsigned)sB0) << shift;
    pmask |= 0xFFu << shift;
    rank = sRank;
    __syncthreads();
  }
  const unsigned thr = prefix;           // 128th-largest key; take `rank` of == thr
  if (t == 0) { sCnt = 0; sEq = 0; }
  __syncthreads();
  for (int i = t; i < 1024; i += 256) {
    const unsigned k = keys[i];
    if (k > thr) { const int s = atomicAdd(&sCnt, 1); selEl[s] = i; }
    else if (k == thr) { const int j = atomicAdd(&sEq, 1); if (j < 32) eqIdx[j] = i; }
  }
  __syncthreads();
  if (t == 0) {
    int n = sEq; if (n > 32) n = 32;
    for (int a = 1; a < n; ++a) {        // ascending index sort (ties: smallest idx)
      const int v2 = eqIdx[a]; int b = a - 1;
      while (b >= 0 && eqIdx[b] > v2) { eqIdx[b + 1] = eqIdx[b]; --b; }
      eqIdx[b + 1] = v2;
    }
    for (int r2 = 0; r2 < rank; ++r2) selEl[sCnt + r2] = eqIdx[r2];
  }
  __syncthreads();
  if (t < 128) {
    const int el = selEl[t];
    const int e = q * 1024 + el;
    sel[q * 128 + t] = e;
    const int src = edges[e * 8 + 6];
    const int dst = edges[e * 8 + 7];
    const float soft = ex[e] / segsum[src];
    atomicAdd(&out_score[dst], soft * node_score[src]);
    flag[src] = 1;
  }
  __syncthreads();
  // zero agg rows for selected src (all zeroing precedes all adds: next kernel)
  for (int i = t; i < 128 * 64; i += 256) {
    const int s = i >> 6, d = i & 63;
    const int e = q * 1024 + selEl[s];
    const int src = edges[e * 8 + 6];
    agg[(size_t)src * 64 + d] = 0.f;
  }
}

// ---------------- scatter: agg[src] += soft * repr[dst] ----------------
__global__ __launch_bounds__(256) void k_scatter(const int* __restrict__ sel,
                                                 const int* __restrict__ edges,
                                                 const float* __restrict__ ex,
                                                 const float* __restrict__ segsum,
                                                 const float* __restrict__ repr,
                                                 float* agg) {
  const int i = blockIdx.x * 4 + (threadIdx.x >> 6);   // selected slot
  const int d = threadIdx.x & 63;
  const int e = sel[i];
  const int src = edges[e * 8 + 6];
  const int dst = edges[e * 8 + 7];
  const float soft = ex[e] / segsum[src];
  atomicAdd(&agg[(size_t)src * 64 + d], soft * repr[(size_t)dst * 64 + d]);
}

// ---------------- final: out = leakyrelu(upd @ W_lin + b) ----------------
#define FN 192
__global__ __launch_bounds__(192) void k_final(const float* __restrict__ repr,
                                               const float* agg,      // aliases outr
                                               const int* __restrict__ flag,
                                               const float* __restrict__ Wl,
                                               const float* __restrict__ bl,
                                               float* outr) {
  __shared__ float Ut[64][FN];
  __shared__ float W[64][64];
  __shared__ float bs[64];
  const int t = threadIdx.x;
  const int n0blk = blockIdx.x * FN;
  for (int i = t; i < 4096; i += FN) W[i >> 6][i & 63] = Wl[i];
  if (t < 64) bs[t] = bl[t];
  {
    const int n = n0blk + t;
    const bool ok = n < NNODES;
    const float* rowp = repr;
    if (ok) rowp = (flag[n] ? agg : repr) + (size_t)n * 64;
#pragma unroll
    for (int i = 0; i < 16; ++i) {
      float4 v4 = ok ? ((const float4*)rowp)[i] : float4{0.f, 0.f, 0.f, 0.f};
      const int c = i * 4;
      Ut[c + 0][t] = v4.x; Ut[c + 1][t] = v4.y; Ut[c + 2][t] = v4.z; Ut[c + 3][t] = v4.w;
    }
  }
  __syncthreads();
  const int dg = t & 7, ng = t >> 3;       // 8 d-groups x 24 n-groups
  const int d0 = dg * 8, nb = ng * 8;
  float acc[8][8];
#pragma unroll
  for (int i = 0; i < 8; ++i)
#pragma unroll
    for (int m = 0; m < 8; ++m) acc[i][m] = 0.f;
#pragma unroll 2
  for (int c = 0; c < 64; ++c) {
    const float4 w0 = *(const float4*)&W[c][d0];
    const float4 w1 = *(const float4*)&W[c][d0 + 4];
    const float4 u0 = *(const float4*)&Ut[c][nb];
    const float4 u1 = *(const float4*)&Ut[c][nb + 4];
    fmarow(acc[0], u0.x, w0, w1);
    fmarow(acc[1], u0.y, w0, w1);
    fmarow(acc[2], u0.z, w0, w1);
    fmarow(acc[3], u0.w, w0, w1);
    fmarow(acc[4], u1.x, w0, w1);
    fmarow(acc[5], u1.y, w0, w1);
    fmarow(acc[6], u1.z, w0, w1);
    fmarow(acc[7], u1.w, w0, w1);
  }
  float bb[8];
#pragma unroll
  for (int m = 0; m < 8; ++m) bb[m] = bs[d0 + m];
#pragma unroll
  for (int i = 0; i < 8; ++i) {
    const int n = n0blk + nb + i;
    if (n < NNODES) {
      float o[8];
#pragma unroll
      for (int m = 0; m < 8; ++m) {
        float v = acc[i][m] + bb[m];
        o[m] = v > 0.f ? v : 0.01f * v;
      }
      float4 o0 = {o[0], o[1], o[2], o[3]};
      float4 o1 = {o[4], o[5], o[6], o[7]};
      *(float4*)(outr + (size_t)n * 64 + d0) = o0;
      *(float4*)(outr + (size_t)n * 64 + d0 + 4) = o1;
    }
  }
}

// ---------------- launcher ----------------
extern "C" void kernel_launch(void* const* d_in, const int* in_sizes, int n_in,
                              void* d_out, int out_size, void* d_ws, size_t ws_size,
                              hipStream_t stream) {
  const float* node_score = (const float*)d_in[0];
  const float* node_repr  = (const float*)d_in[1];
  const float* rel_emb    = (const float*)d_in[2];
  const float* qs_emb     = (const float*)d_in[3];
  const float* qr_emb     = (const float*)d_in[4];
  const float* Wq         = (const float*)d_in[5];
  const float* Wk         = (const float*)d_in[6];
  const float* Wl         = (const float*)d_in[7];
  const float* bl         = (const float*)d_in[8];
  const int*   edges      = (const int*)d_in[9];

  float* out_score = (float*)d_out;                 // [200000]
  float* out_repr  = out_score + NNODES;            // [200000 x 64]; doubles as agg

  float* ws = (float*)d_ws;
  size_t o = 0;
  float* Nm      = ws + o; o += 128 * 128;
  float* alpha   = ws + o; o += NQ * 128;
  float* beta    = ws + o; o += NQ * 128;
  float* cv      = ws + o; o += NQ;
  float* exl     = ws + o; o += NE;                 // logits, then exp(l-m)
  unsigned* segmax = (unsigned*)(ws + o); o += NNODES;
  float* segsum  = ws + o; o += NNODES;
  int* sel       = (int*)(ws + o); o += NSEL;
  int* flag      = (int*)(ws + o); o += NNODES;

  k_init<<<(NNODES + 255) / 256, 256, 0, stream>>>(segmax, segsum, flag, out_score);
  k_nmat<<<128, 256, 0, stream>>>(Wq, Wk, Nm);
  k_query<<<NQ, 256, 0, stream>>>(Wq, Wk, qs_emb, qr_emb, alpha, beta, cv);
  k_logits<<<NE / 128, 512, 0, stream>>>(node_repr, rel_emb, edges, Nm, alpha, beta, cv, exl);
  k_segmax<<<NE / 256, 256, 0, stream>>>(exl, edges, segmax);
  k_exsum<<<NE / 256, 256, 0, stream>>>(exl, edges, segmax, segsum);
  k_topk<<<NQ, 256, 0, stream>>>(exl, segsum, edges, node_score, sel, flag, out_score, out_repr);
  k_scatter<<<NSEL / 4, 256, 0, stream>>>(sel, edges, exl, segsum, node_repr, out_repr);
  k_final<<<(NNODES + FN - 1) / FN, FN, 0, stream>>>(node_repr, out_repr, flag, Wl, bl, out_repr);
}

// Round 5
// 175.595 us; speedup vs baseline: 1.2714x; 1.0557x over previous
//
#include <hip/hip_runtime.h>

#define NNODES 200000
#define NQ     128
#define EPQ    1024
#define NE     (NQ*EPQ)
#define TOPK   128
#define NSEL   (NQ*TOPK)

// ---------------- helpers ----------------
__device__ __forceinline__ unsigned fkey(float f) {
  unsigned u = __float_as_uint(f);
  return (u & 0x80000000u) ? ~u : (u | 0x80000000u);
}
__device__ __forceinline__ float fdecode(unsigned k) {
  unsigned u = (k & 0x80000000u) ? (k ^ 0x80000000u) : ~k;
  return __uint_as_float(u);
}
__device__ __forceinline__ void fmarow(float* a, float x, const float4 n0, const float4 n1) {
  a[0] = fmaf(x, n0.x, a[0]); a[1] = fmaf(x, n0.y, a[1]);
  a[2] = fmaf(x, n0.z, a[2]); a[3] = fmaf(x, n0.w, a[3]);
  a[4] = fmaf(x, n1.x, a[4]); a[5] = fmaf(x, n1.y, a[5]);
  a[6] = fmaf(x, n1.z, a[6]); a[7] = fmaf(x, n1.w, a[7]);
}

typedef const __attribute__((address_space(1))) void* gas_ptr;
typedef __attribute__((address_space(3))) void* las_ptr;
__device__ __forceinline__ void gload16(const void* g, void* l) {
  __builtin_amdgcn_global_load_lds((gas_ptr)g, (las_ptr)l, 16, 0, 0);
}

// permuted within-row index for Nm: lane kg reads k=8kg..8kg+7 via two
// conflict-free ds_read_b128 at byte kg*16 and 256+kg*16 of the 512B row.
__device__ __forceinline__ int nperm(int k) {
  const int q = k >> 2, p = k & 3;
  return (q & 1) * 64 + (q >> 1) * 4 + p;
}

// ---------------- init: zero the node tables ----------------
__global__ __launch_bounds__(256) void k_init(unsigned* __restrict__ segmax,
                                              float* __restrict__ segsum,
                                              int* __restrict__ flag,
                                              float* __restrict__ outs) {
  const int i = blockIdx.x * 256 + threadIdx.x;
  if (i < NNODES) { segmax[i] = 0u; segsum[i] = 0.f; flag[i] = 0; outs[i] = 0.f; }
}

// ---------------- N = WqL^T * WkL  (128x128, permuted row layout) ----------------
__global__ __launch_bounds__(256) void k_nmat(const float* __restrict__ Wq,
                                              const float* __restrict__ Wk,
                                              float* __restrict__ Nm) {
  __shared__ float ph[128];
  const int j = blockIdx.x;
  const int k = threadIdx.x & 127;
  const int ih = threadIdx.x >> 7;
  const int i0 = ih * 128;
  float a0 = 0.f, a1 = 0.f, a2 = 0.f, a3 = 0.f;
  for (int i = i0; i < i0 + 128; i += 4) {
    a0 = fmaf(Wq[(i + 0) * 256 + j], Wk[(i + 0) * 256 + k], a0);
    a1 = fmaf(Wq[(i + 1) * 256 + j], Wk[(i + 1) * 256 + k], a1);
    a2 = fmaf(Wq[(i + 2) * 256 + j], Wk[(i + 2) * 256 + k], a2);
    a3 = fmaf(Wq[(i + 3) * 256 + j], Wk[(i + 3) * 256 + k], a3);
  }
  const float p = (a0 + a1) + (a2 + a3);
  if (ih == 0) ph[k] = p;
  __syncthreads();
  if (ih == 1) Nm[j * 128 + nperm(k)] = ph[k] + p;
}

// ---------------- per-query alpha/beta/c ----------------
__global__ __launch_bounds__(256) void k_query(const float* __restrict__ Wq,
                                               const float* __restrict__ Wk,
                                               const float* __restrict__ qs_emb,
                                               const float* __restrict__ qr_emb,
                                               float* __restrict__ alpha,
                                               float* __restrict__ beta,
                                               float* __restrict__ cv) {
  __shared__ float sq[128];
  __shared__ float u[256], v[256];
  const int q = blockIdx.x, t = threadIdx.x;
  if (t < 64) sq[t] = qs_emb[q * 64 + t];
  else if (t < 128) sq[t] = qr_emb[q * 64 + (t - 64)];
  __syncthreads();
  {
    const float4* wq4 = (const float4*)(Wq + t * 256 + 128);
    const float4* wk4 = (const float4*)(Wk + t * 256 + 128);
    const float4* sq4 = (const float4*)sq;
    float uu = 0.f, vv = 0.f;
#pragma unroll 8
    for (int j = 0; j < 32; ++j) {
      const float4 a = wq4[j], b = wk4[j], s = sq4[j];
      uu = fmaf(a.x, s.x, fmaf(a.y, s.y, fmaf(a.z, s.z, fmaf(a.w, s.w, uu))));
      vv = fmaf(b.x, s.x, fmaf(b.y, s.y, fmaf(b.z, s.z, fmaf(b.w, s.w, vv))));
    }
    u[t] = uu; v[t] = vv;
  }
  __syncthreads();
  if (t < 128) {
    float a0 = 0.f, a1 = 0.f, a2 = 0.f, a3 = 0.f;
    for (int i = 0; i < 256; i += 4) {
      a0 = fmaf(Wq[(i + 0) * 256 + t], v[i + 0], a0);
      a1 = fmaf(Wq[(i + 1) * 256 + t], v[i + 1], a1);
      a2 = fmaf(Wq[(i + 2) * 256 + t], v[i + 2], a2);
      a3 = fmaf(Wq[(i + 3) * 256 + t], v[i + 3], a3);
    }
    alpha[q * 128 + t] = (a0 + a1) + (a2 + a3);
  } else {
    const int k = t - 128;
    float b0 = 0.f, b1 = 0.f, b2 = 0.f, b3 = 0.f;
    for (int i = 0; i < 256; i += 4) {
      b0 = fmaf(u[i + 0], Wk[(i + 0) * 256 + k], b0);
      b1 = fmaf(u[i + 1], Wk[(i + 1) * 256 + k], b1);
      b2 = fmaf(u[i + 2], Wk[(i + 2) * 256 + k], b2);
      b3 = fmaf(u[i + 3], Wk[(i + 3) * 256 + k], b3);
    }
    beta[q * 128 + k] = (b0 + b1) + (b2 + b3);
  }
  __syncthreads();
  if (t < 64) {
    float c = u[t] * v[t] + u[t + 64] * v[t + 64] + u[t + 128] * v[t + 128] + u[t + 192] * v[t + 192];
    c += __shfl_xor(c, 32, 64);
    c += __shfl_xor(c, 16, 64);
    c += __shfl_xor(c, 8, 64);
    c += __shfl_xor(c, 4, 64);
    c += __shfl_xor(c, 2, 64);
    c += __shfl_xor(c, 1, 64);
    if (t == 0) cv[q] = c;
  }
}

// ---------------- edge logits: logit = x^T N y + a.x + b.y + c ----------------
// 256 edges/block, 512 threads, thread tile = 8 edges x 8 k (16 FMA / LDS read).
// Full N (64KB) + X tile [256 edges][64 j] (64KB) in LDS; j processed in two
// phases (repr-src j 0..63, then rel j 64..127 restaged into same buffer).
// X staged via global_load_lds with per-edge XOR chunk swizzle (conflict-free
// 4-distinct-address reads); swizzle applied on global source AND ds_read.
__global__ __launch_bounds__(512, 1) void k_logits(
    const float* __restrict__ repr, const float* __restrict__ rel,
    const int* __restrict__ edges, const float* __restrict__ Nm,
    const float* __restrict__ alpha, const float* __restrict__ beta,
    const float* __restrict__ cv, float* __restrict__ logits) {
  __shared__ float Nl[128 * 128];    // full permuted N (64KB)
  __shared__ float Xe[256 * 64];     // per-edge rows, chunk-swizzled (64KB)
  __shared__ float sA[128], sB[128];
  __shared__ int sSrc[256], sDst[256];
  const int t = threadIdx.x;
  const int e0 = blockIdx.x * 256;
  const int q = e0 >> 10;

  // stage all of N (8 rounds x 512 lanes x 16B = 64KB)
  {
    const char* g = (const char*)Nm + (size_t)t * 16;
    char* l = (char*)Nl + (size_t)t * 16;
#pragma unroll
    for (int r = 0; r < 8; ++r) gload16(g + r * 8192, l + r * 8192);
  }

  // stage src/dst/alpha/beta (thread partition)
  if (t < 256) {
    sSrc[t] = edges[(size_t)(e0 + t) * 8 + 6];
    sDst[t] = edges[(size_t)(e0 + t) * 8 + 7];
  } else if (t < 384) {
    sA[t - 256] = alpha[q * 128 + (t - 256)];
  } else {
    sB[t - 384] = beta[q * 128 + (t - 384)];
  }

  // stage phase-A X: repr[src] rows, 8 rounds; lane (elr,c), el = r*32+elr.
  // LDS dest is linear (r*8192 + t*16); global chunk = c ^ ((el>>3)&3).
  const int elr = t >> 4, c = t & 15;
  const int swzst = (elr >> 3) & 3;          // == (el>>3)&3 for all rounds
#pragma unroll
  for (int r = 0; r < 8; ++r) {
    const int el = r * 32 + elr;
    const int src = edges[(size_t)(e0 + el) * 8 + 6];
    const int cg = c ^ swzst;
    gload16((const char*)repr + ((size_t)src * 64 + cg * 4) * 4,
            (char*)Xe + ((size_t)el * 64 + c * 4) * 4);
  }
  __syncthreads();   // N + phase-A X + tables resident

  const int kg = t & 15, eg = t >> 4;        // 16 k-groups x 32 e-groups
  const int k0 = kg * 8, eb = eg * 8;
  const int kf = kg * 4;                     // float offset in permuted N row
  const int swz = eg & 3;                    // read-side chunk swizzle key
  float acc[8][8];
#pragma unroll
  for (int i = 0; i < 8; ++i)
#pragma unroll
    for (int m = 0; m < 8; ++m) acc[i][m] = 0.f;

  // ---- phase A: j = 0..63 ----
#pragma unroll 2
  for (int J = 0; J < 16; ++J) {
    const float* __restrict__ Nr = Nl + (4 * J) * 128;
    float4 n0[4], n1[4];
#pragma unroll
    for (int jj = 0; jj < 4; ++jj) {
      n0[jj] = *(const float4*)(Nr + jj * 128 + kf);
      n1[jj] = *(const float4*)(Nr + jj * 128 + 64 + kf);
    }
    const int ch = (J ^ swz) * 4;
    float4 xv[8];
#pragma unroll
    for (int i = 0; i < 8; ++i)
      xv[i] = *(const float4*)(Xe + (eb + i) * 64 + ch);
#pragma unroll
    for (int jj = 0; jj < 4; ++jj) {
#pragma unroll
      for (int i = 0; i < 8; ++i) {
        const float xs = jj == 0 ? xv[i].x : jj == 1 ? xv[i].y : jj == 2 ? xv[i].z : xv[i].w;
        fmarow(acc[i], xs, n0[jj], n1[jj]);
      }
    }
  }
  __syncthreads();   // all phase-A reads of Xe done

  // restage Xe with rel rows (contiguous in global)
#pragma unroll
  for (int r = 0; r < 8; ++r) {
    const int el = r * 32 + elr;
    const int cg = c ^ swzst;
    gload16((const char*)rel + ((size_t)(e0 + el) * 64 + cg * 4) * 4,
            (char*)Xe + ((size_t)el * 64 + c * 4) * 4);
  }
  __syncthreads();   // phase-B X resident

  // ---- phase B: j = 64..127 ----
#pragma unroll 2
  for (int J = 0; J < 16; ++J) {
    const float* __restrict__ Nr = Nl + (64 + 4 * J) * 128;
    float4 n0[4], n1[4];
#pragma unroll
    for (int jj = 0; jj < 4; ++jj) {
      n0[jj] = *(const float4*)(Nr + jj * 128 + kf);
      n1[jj] = *(const float4*)(Nr + jj * 128 + 64 + kf);
    }
    const int ch = (J ^ swz) * 4;
    float4 xv[8];
#pragma unroll
    for (int i = 0; i < 8; ++i)
      xv[i] = *(const float4*)(Xe + (eb + i) * 64 + ch);
#pragma unroll
    for (int jj = 0; jj < 4; ++jj) {
#pragma unroll
      for (int i = 0; i < 8; ++i) {
        const float xs = jj == 0 ? xv[i].x : jj == 1 ? xv[i].y : jj == 2 ? xv[i].z : xv[i].w;
        fmarow(acc[i], xs, n0[jj], n1[jj]);
      }
    }
  }

  float aA[8], aB[8];
#pragma unroll
  for (int m = 0; m < 8; ++m) { aA[m] = sA[k0 + m]; aB[m] = sB[k0 + m]; }

  float part[8];
#pragma unroll
  for (int i = 0; i < 8; ++i) {
    const int el = eb + i;
    const int e = e0 + el;
    const float* xp;
    const float* yp;
    if (k0 < 64) {
      xp = repr + (size_t)sSrc[el] * 64 + k0;
      yp = repr + (size_t)sDst[el] * 64 + k0;
    } else {
      xp = rel + (size_t)e * 64 + (k0 - 64);
      yp = xp;
    }
    const float4 x0 = *(const float4*)xp;
    const float4 x1 = *(const float4*)(xp + 4);
    const float4 y0 = *(const float4*)yp;
    const float4 y1 = *(const float4*)(yp + 4);
    const float xs[8] = {x0.x, x0.y, x0.z, x0.w, x1.x, x1.y, x1.z, x1.w};
    const float ys[8] = {y0.x, y0.y, y0.z, y0.w, y1.x, y1.y, y1.z, y1.w};
    float p = 0.f;
#pragma unroll
    for (int m = 0; m < 8; ++m)
      p += (acc[i][m] + aB[m]) * ys[m] + aA[m] * xs[m];
    part[i] = p;
  }
#pragma unroll
  for (int i = 0; i < 8; ++i) {
    float p = part[i];
    p += __shfl_xor(p, 8, 64);
    p += __shfl_xor(p, 4, 64);
    p += __shfl_xor(p, 2, 64);
    p += __shfl_xor(p, 1, 64);
    part[i] = p;
  }
  if (kg == 0) {
    const float cq = cv[q];
    float4 o0 = {part[0] + cq, part[1] + cq, part[2] + cq, part[3] + cq};
    float4 o1 = {part[4] + cq, part[5] + cq, part[6] + cq, part[7] + cq};
    *(float4*)(logits + e0 + eb) = o0;
    *(float4*)(logits + e0 + eb + 4) = o1;
  }
}

// ---------------- segment softmax (by src) ----------------
__global__ __launch_bounds__(256) void k_segmax(const float* __restrict__ logits,
                                                const int* __restrict__ edges,
                                                unsigned* __restrict__ segmax) {
  const int e = blockIdx.x * 256 + threadIdx.x;
  const int src = edges[(size_t)e * 8 + 6];
  atomicMax(&segmax[src], fkey(logits[e]));
}

__global__ __launch_bounds__(256) void k_exsum(float* __restrict__ logits,
                                               const int* __restrict__ edges,
                                               const unsigned* __restrict__ segmax,
                                               float* __restrict__ segsum) {
  const int e = blockIdx.x * 256 + threadIdx.x;
  const int src = edges[(size_t)e * 8 + 6];
  const float m = fdecode(segmax[src]);
  const float ex = expf(logits[e] - m);
  logits[e] = ex;                       // in-place: now holds exp(l - m)
  atomicAdd(&segsum[src], ex);
}

// ---------------- per-query top-128: 4-pass radix select (exact tie-break) -----
__global__ __launch_bounds__(256) void k_topk(const float* __restrict__ ex,
                                              const float* __restrict__ segsum,
                                              const int* __restrict__ edges,
                                              const float* __restrict__ node_score,
                                              int* __restrict__ sel,
                                              int* __restrict__ flag,
                                              float* __restrict__ out_score,
                                              float* agg) {
  __shared__ unsigned keys[1024];
  __shared__ int hist[256];
  __shared__ int selEl[128];
  __shared__ int eqIdx[32];
  __shared__ int sB0, sRank, sCnt, sEq;
  const int q = blockIdx.x, t = threadIdx.x;
  for (int i = t; i < 1024; i += 256) {
    const int e = q * 1024 + i;
    const int src = edges[(size_t)e * 8 + 6];
    const float ts = (ex[e] / segsum[src]) * node_score[src];
    keys[i] = fkey(ts);
  }
  unsigned prefix = 0, pmask = 0;
  int rank = 128;                 // rank-th largest among candidates
  __syncthreads();
#pragma unroll
  for (int pass = 0; pass < 4; ++pass) {
    const int shift = 24 - 8 * pass;
    hist[t] = 0;
    __syncthreads();
    for (int i = t; i < 1024; i += 256) {
      const unsigned k = keys[i];
      if ((k & pmask) == prefix) atomicAdd(&hist[(k >> shift) & 255], 1);
    }
    __syncthreads();
    if (t < 64) {
      const int h0 = hist[4 * t], h1 = hist[4 * t + 1], h2 = hist[4 * t + 2], h3 = hist[4 * t + 3];
      const int s4 = h0 + h1 + h2 + h3;
      int S = s4;
      for (int d = 1; d < 64; d <<= 1) {
        const int o = __shfl_down(S, d, 64);
        if (t + d < 64) S += o;
      }
      const int Snext = S - s4;          // suffix sum excluding this lane's bins
      if (S >= rank && Snext < rank) {   // exactly one lane crosses
        int r = rank - Snext;            // r-th from top within these 4 bins
        int b;
        if (r <= h3) b = 3;
        else if (r <= h3 + h2) { b = 2; r -= h3; }
        else if (r <= h3 + h2 + h1) { b = 1; r -= h3 + h2; }
        else { b = 0; r -= h3 + h2 + h1; }
        sB0 = 4 * t + b; sRank = r;
      }
    }
    __syncthreads();
    prefix |= ((unsigned)sB0) << shift;
    pmask |= 0xFFu << shift;
    rank = sRank;
    __syncthreads();
  }
  const unsigned thr = prefix;           // 128th-largest key; take `rank` of == thr
  if (t == 0) { sCnt = 0; sEq = 0; }
  __syncthreads();
  for (int i = t; i < 1024; i += 256) {
    const unsigned k = keys[i];
    if (k > thr) { const int s = atomicAdd(&sCnt, 1); selEl[s] = i; }
    else if (k == thr) { const int j = atomicAdd(&sEq, 1); if (j < 32) eqIdx[j] = i; }
  }
  __syncthreads();
  if (t == 0) {
    int n = sEq; if (n > 32) n = 32;
    for (int a = 1; a < n; ++a) {        // ascending index sort (ties: smallest idx)
      const int v2 = eqIdx[a]; int b = a - 1;
      while (b >= 0 && eqIdx[b] > v2) { eqIdx[b + 1] = eqIdx[b]; --b; }
      eqIdx[b + 1] = v2;
    }
    for (int r2 = 0; r2 < rank; ++r2) selEl[sCnt + r2] = eqIdx[r2];
  }
  __syncthreads();
  if (t < 128) {
    const int el = selEl[t];
    const int e = q * 1024 + el;
    sel[q * 128 + t] = e;
    const int src = edges[(size_t)e * 8 + 6];
    const int dst = edges[(size_t)e * 8 + 7];
    const float soft = ex[e] / segsum[src];
    atomicAdd(&out_score[dst], soft * node_score[src]);
    flag[src] = 1;
  }
  __syncthreads();
  // zero agg rows for selected src (all zeroing precedes all adds: next kernel)
  for (int i = t; i < 128 * 64; i += 256) {
    const int s = i >> 6, d = i & 63;
    const int e = q * 1024 + selEl[s];
    const int src = edges[(size_t)e * 8 + 6];
    agg[(size_t)src * 64 + d] = 0.f;
  }
}

// ---------------- scatter: agg[src] += soft * repr[dst] ----------------
__global__ __launch_bounds__(256) void k_scatter(const int* __restrict__ sel,
                                                 const int* __restrict__ edges,
                                                 const float* __restrict__ ex,
                                                 const float* __restrict__ segsum,
                                                 const float* __restrict__ repr,
                                                 float* agg) {
  const int i = blockIdx.x * 4 + (threadIdx.x >> 6);   // selected slot
  const int d = threadIdx.x & 63;
  const int e = sel[i];
  const int src = edges[(size_t)e * 8 + 6];
  const int dst = edges[(size_t)e * 8 + 7];
  const float soft = ex[e] / segsum[src];
  atomicAdd(&agg[(size_t)src * 64 + d], soft * repr[(size_t)dst * 64 + d]);
}

// ---------------- final: out = leakyrelu(upd @ W_lin + b) ----------------
#define FN 192
__global__ __launch_bounds__(192) void k_final(const float* __restrict__ repr,
                                               const float* agg,      // aliases outr
                                               const int* __restrict__ flag,
                                               const float* __restrict__ Wl,
                                               const float* __restrict__ bl,
                                               float* outr) {
  __shared__ float Ut[64][FN];
  __shared__ float W[64][64];
  __shared__ float bs[64];
  const int t = threadIdx.x;
  const int n0blk = blockIdx.x * FN;
  for (int i = t; i < 4096; i += FN) W[i >> 6][i & 63] = Wl[i];
  if (t < 64) bs[t] = bl[t];
  {
    const int n = n0blk + t;
    const bool ok = n < NNODES;
    const float* rowp = repr;
    if (ok) rowp = (flag[n] ? agg : repr) + (size_t)n * 64;
#pragma unroll
    for (int i = 0; i < 16; ++i) {
      float4 v4 = ok ? ((const float4*)rowp)[i] : float4{0.f, 0.f, 0.f, 0.f};
      const int c = i * 4;
      Ut[c + 0][t] = v4.x; Ut[c + 1][t] = v4.y; Ut[c + 2][t] = v4.z; Ut[c + 3][t] = v4.w;
    }
  }
  __syncthreads();
  const int dg = t & 7, ng = t >> 3;       // 8 d-groups x 24 n-groups
  const int d0 = dg * 8, nb = ng * 8;
  float acc[8][8];
#pragma unroll
  for (int i = 0; i < 8; ++i)
#pragma unroll
    for (int m = 0; m < 8; ++m) acc[i][m] = 0.f;
#pragma unroll 2
  for (int c = 0; c < 64; ++c) {
    const float4 w0 = *(const float4*)&W[c][d0];
    const float4 w1 = *(const float4*)&W[c][d0 + 4];
    const float4 u0 = *(const float4*)&Ut[c][nb];
    const float4 u1 = *(const float4*)&Ut[c][nb + 4];
    fmarow(acc[0], u0.x, w0, w1);
    fmarow(acc[1], u0.y, w0, w1);
    fmarow(acc[2], u0.z, w0, w1);
    fmarow(acc[3], u0.w, w0, w1);
    fmarow(acc[4], u1.x, w0, w1);
    fmarow(acc[5], u1.y, w0, w1);
    fmarow(acc[6], u1.z, w0, w1);
    fmarow(acc[7], u1.w, w0, w1);
  }
  float bb[8];
#pragma unroll
  for (int m = 0; m < 8; ++m) bb[m] = bs[d0 + m];
#pragma unroll
  for (int i = 0; i < 8; ++i) {
    const int n = n0blk + nb + i;
    if (n < NNODES) {
      float o[8];
#pragma unroll
      for (int m = 0; m < 8; ++m) {
        float v = acc[i][m] + bb[m];
        o[m] = v > 0.f ? v : 0.01f * v;
      }
      float4 o0 = {o[0], o[1], o[2], o[3]};
      float4 o1 = {o[4], o[5], o[6], o[7]};
      *(float4*)(outr + (size_t)n * 64 + d0) = o0;
      *(float4*)(outr + (size_t)n * 64 + d0 + 4) = o1;
    }
  }
}

// ---------------- launcher ----------------
extern "C" void kernel_launch(void* const* d_in, const int* in_sizes, int n_in,
                              void* d_out, int out_size, void* d_ws, size_t ws_size,
                              hipStream_t stream) {
  const float* node_score = (const float*)d_in[0];
  const float* node_repr  = (const float*)d_in[1];
  const float* rel_emb    = (const float*)d_in[2];
  const float* qs_emb     = (const float*)d_in[3];
  const float* qr_emb     = (const float*)d_in[4];
  const float* Wq         = (const float*)d_in[5];
  const float* Wk         = (const float*)d_in[6];
  const float* Wl         = (const float*)d_in[7];
  const float* bl         = (const float*)d_in[8];
  const int*   edges      = (const int*)d_in[9];

  float* out_score = (float*)d_out;                 // [200000]
  float* out_repr  = out_score + NNODES;            // [200000 x 64]; doubles as agg

  float* ws = (float*)d_ws;
  size_t o = 0;
  float* Nm      = ws + o; o += 128 * 128;
  float* alpha   = ws + o; o += NQ * 128;
  float* beta    = ws + o; o += NQ * 128;
  float* cv      = ws + o; o += NQ;
  float* exl     = ws + o; o += NE;                 // logits, then exp(l-m)
  unsigned* segmax = (unsigned*)(ws + o); o += NNODES;
  float* segsum  = ws + o; o += NNODES;
  int* sel       = (int*)(ws + o); o += NSEL;
  int* flag      = (int*)(ws + o); o += NNODES;

  k_init<<<(NNODES + 255) / 256, 256, 0, stream>>>(segmax, segsum, flag, out_score);
  k_nmat<<<128, 256, 0, stream>>>(Wq, Wk, Nm);
  k_query<<<NQ, 256, 0, stream>>>(Wq, Wk, qs_emb, qr_emb, alpha, beta, cv);
  k_logits<<<NE / 256, 512, 0, stream>>>(node_repr, rel_emb, edges, Nm, alpha, beta, cv, exl);
  k_segmax<<<NE / 256, 256, 0, stream>>>(exl, edges, segmax);
  k_exsum<<<NE / 256, 256, 0, stream>>>(exl, edges, segmax, segsum);
  k_topk<<<NQ, 256, 0, stream>>>(exl, segsum, edges, node_score, sel, flag, out_score, out_repr);
  k_scatter<<<NSEL / 4, 256, 0, stream>>>(sel, edges, exl, segsum, node_repr, out_repr);
  k_final<<<(NNODES + FN - 1) / FN, FN, 0, stream>>>(node_repr, out_repr, flag, Wl, bl, out_repr);
}